// Round 14
// baseline (310.388 us; speedup 1.0000x reference)
//
#include <hip/hip_runtime.h>
#include <hip/hip_bf16.h>
#include <stdint.h>

#define BB 8
#define NN 2048

// ---- workspace layout ----
#define OFF_B1 272
#define OFF_B2 4432
#define OFF_B3 12688
#define IDX_BYTE_OFF 65536            // u16 idx[B][N][64] = 2 MiB
#define T_BASE   (65536 + 2*1024*1024)
#define T1_OFF   T_BASE               // [64][32] bf16, 4096 B
#define T2H_OFF  (T1_OFF + 4096)      // [64][72] bf16, K-permuted
#define T2L_OFF  (T2H_OFF + 9216)
#define T3H_OFF  (T2L_OFF + 9216)     // [128][72] bf16, K-permuted
#define T3L_OFF  (T3H_OFF + 18432)

typedef __attribute__((ext_vector_type(4))) float f32x4;
typedef __attribute__((ext_vector_type(8))) short s16x8;
typedef __attribute__((ext_vector_type(8))) uint32_t u32v8;

__device__ __forceinline__ float ldany(const void* p, long i, int isf32) {
    if (isf32) return ((const float*)p)[i];
    uint32_t u = ((uint32_t)((const uint16_t*)p)[i]) << 16;
    float f; __builtin_memcpy(&f, &u, 4); return f;
}
__device__ __forceinline__ uint16_t f2bf(float f) {
    uint32_t u; __builtin_memcpy(&u, &f, 4);
    return (uint16_t)((u + 0x7FFFu + ((u >> 16) & 1u)) >> 16);
}
__device__ __forceinline__ float bf2f(uint16_t h) {
    uint32_t u = ((uint32_t)h) << 16;
    float f; __builtin_memcpy(&f, &u, 4); return f;
}
__device__ __forceinline__ uint32_t pk2(float a, float b) {
    __hip_bfloat162 h = __float22bfloat162_rn(make_float2(a, b));
    uint32_t u; __builtin_memcpy(&u, &h, 4); return u;
}
__device__ __forceinline__ s16x8 mk8(uint32_t a, uint32_t b, uint32_t c, uint32_t d) {
    uint32_t t[4] = {a, b, c, d}; s16x8 r; __builtin_memcpy(&r, t, 16); return r;
}
__device__ __forceinline__ float sane(float v) {
    return (v == v && v > -1e30f && v < 1e30f) ? v : 0.f;
}
__device__ __forceinline__ int mbcnt64(unsigned long long m) {
    return __builtin_amdgcn_mbcnt_hi((uint32_t)(m >> 32),
           __builtin_amdgcn_mbcnt_lo((uint32_t)m, 0));
}
__device__ __forceinline__ int kperm_pos(int kk) {
    int g = kk >> 5, c5 = kk & 31;
    int sub = (c5 >> 4) & 1, q = (c5 >> 2) & 3, r = c5 & 3;
    return 32 * g + 8 * q + 4 * sub + r;
}

// one candidate distance -> f32 bits into vector slot (literal index)
#define D2ONE(r, slot, u_x, u_y, u_z)                                          \
    {                                                                          \
        uint32_t ux = (u_x), uy = (u_y), uz = (u_z);                           \
        float nx, ny, nz;                                                      \
        __builtin_memcpy(&nx, &ux, 4);                                         \
        __builtin_memcpy(&ny, &uy, 4);                                         \
        __builtin_memcpy(&nz, &uz, 4);                                         \
        float s2 = nx * nx + ny * ny + nz * nz;                                \
        float dt = qx * nx + qy * ny + qz * nz;                                \
        float d2 = fmaxf((s1 + s2) - 2.0f * dt, 0.0f);                         \
        uint32_t bits; __builtin_memcpy(&bits, &d2, 4);                        \
        r[slot] = bits;                                                        \
    }

// bf16 chunk: 4x uint4 (x,y,z rows) -> 8 candidate d2-bit values
__device__ __forceinline__ u32v8 d2chunk(uint4 X, uint4 Y, uint4 Z,
                                         float qx, float qy, float qz, float s1) {
    u32v8 r;
    D2ONE(r, 0, X.x << 16, Y.x << 16, Z.x << 16)
    D2ONE(r, 1, X.x & 0xFFFF0000u, Y.x & 0xFFFF0000u, Z.x & 0xFFFF0000u)
    D2ONE(r, 2, X.y << 16, Y.y << 16, Z.y << 16)
    D2ONE(r, 3, X.y & 0xFFFF0000u, Y.y & 0xFFFF0000u, Z.y & 0xFFFF0000u)
    D2ONE(r, 4, X.z << 16, Y.z << 16, Z.z << 16)
    D2ONE(r, 5, X.z & 0xFFFF0000u, Y.z & 0xFFFF0000u, Z.z & 0xFFFF0000u)
    D2ONE(r, 6, X.w << 16, Y.w << 16, Z.w << 16)
    D2ONE(r, 7, X.w & 0xFFFF0000u, Y.w & 0xFFFF0000u, Z.w & 0xFFFF0000u)
    return r;
}

#define F32ONE(r, slot, jj)                                                    \
    {                                                                          \
        float nx = ((const float*)tp)[base + (jj)];                            \
        float ny = ((const float*)tp)[base + NN + (jj)];                       \
        float nz = ((const float*)tp)[base + 2*NN + (jj)];                     \
        float s2 = nx * nx + ny * ny + nz * nz;                                \
        float dt = qx * nx + qy * ny + qz * nz;                                \
        float d2 = fmaxf((s1 + s2) - 2.0f * dt, 0.0f);                         \
        uint32_t bits; __builtin_memcpy(&bits, &d2, 4);                        \
        r[slot] = bits;                                                        \
    }

__device__ __forceinline__ u32v8 d2chunk_f32(const void* tp, long base, int i0, int lane,
                                             float qx, float qy, float qz, float s1) {
    u32v8 r;
    F32ONE(r, 0, (i0 + 0) * 64 + lane)
    F32ONE(r, 1, (i0 + 1) * 64 + lane)
    F32ONE(r, 2, (i0 + 2) * 64 + lane)
    F32ONE(r, 3, (i0 + 3) * 64 + lane)
    F32ONE(r, 4, (i0 + 4) * 64 + lane)
    F32ONE(r, 5, (i0 + 5) * 64 + lane)
    F32ONE(r, 6, (i0 + 6) * 64 + lane)
    F32ONE(r, 7, (i0 + 7) * 64 + lane)
    return r;
}

#define CNT8(v, mid)                                                           \
    (__builtin_popcountll(__ballot((v)[0] < (mid))) +                          \
     __builtin_popcountll(__ballot((v)[1] < (mid))) +                          \
     __builtin_popcountll(__ballot((v)[2] < (mid))) +                          \
     __builtin_popcountll(__ballot((v)[3] < (mid))) +                          \
     __builtin_popcountll(__ballot((v)[4] < (mid))) +                          \
     __builtin_popcountll(__ballot((v)[5] < (mid))) +                          \
     __builtin_popcountll(__ballot((v)[6] < (mid))) +                          \
     __builtin_popcountll(__ballot((v)[7] < (mid))))

#define SCAT1(v, slot, CB, tau, sl, basePos)                                   \
    {                                                                          \
        bool p = (v)[slot] < (tau);                                            \
        unsigned long long m = __ballot(p);                                    \
        int pos = (basePos) + mbcnt64(m);                                      \
        unsigned idxv = isf32 ? (unsigned)((8 * (CB) + (slot)) * 64 + lane)    \
                              : (unsigned)(512 * (CB) + 8 * lane + (slot));    \
        if (p && pos < 64) sl[pos] =                                           \
            (((unsigned long long)(v)[slot]) << 32) | idxv;                    \
        basePos += __builtin_popcountll(m);                                    \
    }

#define SCAT8(v, CB, tau, sl, basePos)                                         \
    SCAT1(v, 0, CB, tau, sl, basePos) SCAT1(v, 1, CB, tau, sl, basePos)        \
    SCAT1(v, 2, CB, tau, sl, basePos) SCAT1(v, 3, CB, tau, sl, basePos)        \
    SCAT1(v, 4, CB, tau, sl, basePos) SCAT1(v, 5, CB, tau, sl, basePos)        \
    SCAT1(v, 6, CB, tau, sl, basePos) SCAT1(v, 7, CB, tau, sl, basePos)

// ---------------- K0: parallel dtype detect + fold + padded K-permuted tables (R11-proven) ----------------
__global__ void k0_fold(const void* p1,
                        const void* W1, const void* b1, const void* g1, const void* be1, const void* m1, const void* v1,
                        const void* W2, const void* b2, const void* g2, const void* be2, const void* m2, const void* v2,
                        const void* W3, const void* b3, const void* g3, const void* be3, const void* m3, const void* v3,
                        float* wsf, int* wsi) {
    __shared__ int s_cnt;
    int t = threadIdx.x;
    if (t == 0) s_cnt = 0;
    __syncthreads();
    const uint16_t* u = (const uint16_t*)p1;
    int c = 0;
    for (int i = t; i < 4096; i += 256) {
        uint16_t x = u[i];
        uint32_t e = (x >> 7) & 0xFF;
        c += ((e >= 0x70 && e <= 0x84) || x == 0) ? 1 : 0;
    }
    atomicAdd(&s_cnt, c);
    __syncthreads();
    int isf32 = (s_cnt < 3686) ? 1 : 0;
    if (blockIdx.x == 0 && t == 0) wsi[0] = isf32;

    uint16_t* t1  = (uint16_t*)((char*)wsf + T1_OFF);
    uint16_t* t2h = (uint16_t*)((char*)wsf + T2H_OFF);
    uint16_t* t2l = (uint16_t*)((char*)wsf + T2L_OFF);
    uint16_t* t3h = (uint16_t*)((char*)wsf + T3H_OFF);
    uint16_t* t3l = (uint16_t*)((char*)wsf + T3L_OFF);

    int gid = blockIdx.x * 256 + t;
    if (gid < 4096) {
        int o = gid >> 6, kk = gid & 63;
        float s = ldany(g2, o, isf32) * rsqrtf(ldany(v2, o, isf32) + 1e-3f);
        float w = ldany(W2, gid, isf32) * s;
        uint16_t wh = f2bf(w);
        int pos = o * 72 + kperm_pos(kk);
        t2h[pos] = wh; t2l[pos] = f2bf(w - bf2f(wh));
    } else if (gid < 12288) {
        int e = gid - 4096;
        int o = e >> 6, kk = e & 63;
        float s = ldany(g3, o, isf32) * rsqrtf(ldany(v3, o, isf32) + 1e-3f);
        float w = ldany(W3, e, isf32) * s;
        uint16_t wh = f2bf(w);
        int pos = o * 72 + kperm_pos(kk);
        t3h[pos] = wh; t3l[pos] = f2bf(w - bf2f(wh));
    } else if (gid < 12544) {
        int e = gid - 12288;
        int co = e >> 2, cc = e & 3;
        float s = ldany(g1, co, isf32) * rsqrtf(ldany(v1, co, isf32) + 1e-3f);
        float w = ldany(W1, co*4 + cc, isf32) * s;
        uint16_t wh = f2bf(w), wl = f2bf(w - bf2f(wh));
        t1[co*32 + cc]     = wh;
        t1[co*32 + 4 + cc] = wh;
        t1[co*32 + 8 + cc] = wl;
    } else if (gid < 13824) {
        int e = gid - 12544;
        int co = e / 20, k = e - co * 20;
        t1[co*32 + 12 + k] = 0;
    } else if (gid < 13888) {
        int o = gid - 13824;
        float s = ldany(g1, o, isf32) * rsqrtf(ldany(v1, o, isf32) + 1e-3f);
        wsf[OFF_B1 + o] = (ldany(b1, o, isf32) - ldany(m1, o, isf32)) * s + ldany(be1, o, isf32);
    } else if (gid < 13952) {
        int o = gid - 13888;
        float s = ldany(g2, o, isf32) * rsqrtf(ldany(v2, o, isf32) + 1e-3f);
        wsf[OFF_B2 + o] = (ldany(b2, o, isf32) - ldany(m2, o, isf32)) * s + ldany(be2, o, isf32);
    } else if (gid < 14080) {
        int o = gid - 13952;
        float s = ldany(g3, o, isf32) * rsqrtf(ldany(v3, o, isf32) + 1e-3f);
        wsf[OFF_B3 + o] = (ldany(b3, o, isf32) - ldany(m3, o, isf32)) * s + ldany(be3, o, isf32);
    }
}

// ---------------- K1: dual-target exact top-32 KNN — ext_vector registers (no alloca) ----------------
__launch_bounds__(256, 4)
__global__ void k1_knn(const void* p1, const void* p2, const int* wsi, uint16_t* idxout) {
    __shared__ unsigned long long smem[4 * 128];

    int isf32 = wsi[0];
    int lane = threadIdx.x & 63;
    int wave = threadIdx.x >> 6;
    int qidx = blockIdx.x * 4 + wave;
    int b = qidx >> 11, n = qidx & 2047;
    long base = (long)b * 3 * NN;

    float qx = ldany(p1, base + n,        isf32);
    float qy = ldany(p1, base + NN + n,   isf32);
    float qz = ldany(p1, base + 2*NN + n, isf32);
    float s1 = qx * qx + qy * qy + qz * qz;

    u32v8 kA0, kA1, kA2, kA3, kB0, kB1, kB2, kB3;
    if (!isf32) {
        {
            const uint16_t* tpu = (const uint16_t*)p1 + base;
            const uint4* rx = (const uint4*)(tpu);
            const uint4* ry = (const uint4*)(tpu + NN);
            const uint4* rz = (const uint4*)(tpu + 2*NN);
            kA0 = d2chunk(rx[lane],       ry[lane],       rz[lane],       qx, qy, qz, s1);
            kA1 = d2chunk(rx[64 + lane],  ry[64 + lane],  rz[64 + lane],  qx, qy, qz, s1);
            kA2 = d2chunk(rx[128 + lane], ry[128 + lane], rz[128 + lane], qx, qy, qz, s1);
            kA3 = d2chunk(rx[192 + lane], ry[192 + lane], rz[192 + lane], qx, qy, qz, s1);
        }
        {
            const uint16_t* tpu = (const uint16_t*)p2 + base;
            const uint4* rx = (const uint4*)(tpu);
            const uint4* ry = (const uint4*)(tpu + NN);
            const uint4* rz = (const uint4*)(tpu + 2*NN);
            kB0 = d2chunk(rx[lane],       ry[lane],       rz[lane],       qx, qy, qz, s1);
            kB1 = d2chunk(rx[64 + lane],  ry[64 + lane],  rz[64 + lane],  qx, qy, qz, s1);
            kB2 = d2chunk(rx[128 + lane], ry[128 + lane], rz[128 + lane], qx, qy, qz, s1);
            kB3 = d2chunk(rx[192 + lane], ry[192 + lane], rz[192 + lane], qx, qy, qz, s1);
        }
    } else {
        kA0 = d2chunk_f32(p1, base, 0,  lane, qx, qy, qz, s1);
        kA1 = d2chunk_f32(p1, base, 8,  lane, qx, qy, qz, s1);
        kA2 = d2chunk_f32(p1, base, 16, lane, qx, qy, qz, s1);
        kA3 = d2chunk_f32(p1, base, 24, lane, qx, qy, qz, s1);
        kB0 = d2chunk_f32(p2, base, 0,  lane, qx, qy, qz, s1);
        kB1 = d2chunk_f32(p2, base, 8,  lane, qx, qy, qz, s1);
        kB2 = d2chunk_f32(p2, base, 16, lane, qx, qy, qz, s1);
        kB3 = d2chunk_f32(p2, base, 24, lane, qx, qy, qz, s1);
    }

    // ---- dual windowed bisection (accept count in [32,64]) — ballot counting ----
    uint32_t loA = 0u, hiA = 0x7F800001u, tauA = 0u;
    uint32_t loB = 0u, hiB = 0x7F800001u, tauB = 0u;
    bool dA = false, dB = false;
    while (!(dA && dB)) {
        uint32_t midA = loA + ((hiA - loA) >> 1);
        uint32_t midB = loB + ((hiB - loB) >> 1);
        int cA = CNT8(kA0, midA) + CNT8(kA1, midA) + CNT8(kA2, midA) + CNT8(kA3, midA);
        int cB = CNT8(kB0, midB) + CNT8(kB1, midB) + CNT8(kB2, midB) + CNT8(kB3, midB);
        if (!dA) {
            if (cA < 32)      loA = midA;
            else if (cA > 64) hiA = midA;
            else { tauA = midA; dA = true; }
            if (!dA && hiA - loA <= 1u) { tauA = hiA; dA = true; }
        }
        if (!dB) {
            if (cB < 32)      loB = midB;
            else if (cB > 64) hiB = midB;
            else { tauB = midB; dB = true; }
            if (!dB && hiB - loB <= 1u) { tauB = hiB; dB = true; }
        }
    }

    // ---- survivors -> LDS via ballot+mbcnt ranks, sentinel fill ----
    unsigned long long* slA = smem + wave * 128;
    unsigned long long* slB = slA + 64;
    slA[lane] = ~0ull;
    slB[lane] = ~0ull;
    __syncthreads();
    {
        int baseA = 0;
        SCAT8(kA0, 0, tauA, slA, baseA)
        SCAT8(kA1, 1, tauA, slA, baseA)
        SCAT8(kA2, 2, tauA, slA, baseA)
        SCAT8(kA3, 3, tauA, slA, baseA)
        int baseB = 0;
        SCAT8(kB0, 0, tauB, slB, baseB)
        SCAT8(kB1, 1, tauB, slB, baseB)
        SCAT8(kB2, 2, tauB, slB, baseB)
        SCAT8(kB3, 3, tauB, slB, baseB)
    }
    __syncthreads();
    unsigned long long keyA = slA[lane];
    unsigned long long keyB = slB[lane];

    // ---- interleaved dual bitonic sort 64 (ascending (d2bits, idx)) — R9-proven ----
    #pragma unroll
    for (int sz = 2; sz <= 64; sz <<= 1) {
        #pragma unroll
        for (int st = sz >> 1; st > 0; st >>= 1) {
            bool up    = ((lane & sz) == 0);
            bool lower = ((lane & st) == 0);
            unsigned long long otA = __shfl_xor(keyA, st, 64);
            unsigned long long otB = __shfl_xor(keyB, st, 64);
            unsigned long long mnA = (keyA < otA) ? keyA : otA;
            unsigned long long mxA = (keyA < otA) ? otA : keyA;
            keyA = (lower == up) ? mnA : mxA;
            unsigned long long mnB = (keyB < otB) ? keyB : otB;
            unsigned long long mxB = (keyB < otB) ? otB : keyB;
            keyB = (lower == up) ? mnB : mxB;
        }
    }

    if (lane < 32) {
        long obase = ((long)qidx) << 6;
        idxout[obase + lane]      = (uint16_t)(keyA & 0x7FFu);
        idxout[obase + 32 + lane] = (uint16_t)(keyB & 0x7FFu);
    }
}

// ---------------- K2: MFMA MLP — T3 in LDS (4 blocks/CU), T1/T2 from L2 ----------------
__launch_bounds__(256, 4)
__global__ void k2_mlp(const void* p1, const void* p2, const float* __restrict__ wsf, const int* wsi,
                       const uint16_t* __restrict__ idxin, void* outp) {
    __shared__ uint4 shw4[2304];   // T3H+T3L: 2*128*72*2 = 36864 B

    {
        const uint4* src = (const uint4*)((const char*)wsf + T3H_OFF);
        for (int i = threadIdx.x; i < 2304; i += 256) shw4[i] = src[i];
    }
    __syncthreads();
    const uint16_t* T3H = (const uint16_t*)shw4;
    const uint16_t* T3L = T3H + 9216;
    const uint16_t* T1  = (const uint16_t*)((const char*)wsf + T1_OFF);
    const uint16_t* T2H = (const uint16_t*)((const char*)wsf + T2H_OFF);
    const uint16_t* T2L = (const uint16_t*)((const char*)wsf + T2L_OFF);

    int isf32 = wsi[0];
    int lane = threadIdx.x & 63;
    int wave = threadIdx.x >> 6;
    int c = lane & 15;
    int q = lane >> 4;
    int qidx = blockIdx.x * 4 + wave;
    int b = qidx >> 11, n = qidx & 2047;
    long base = (long)b * 3 * NN;

    float qx = sane(ldany(p1, base + n,        isf32));
    float qy = sane(ldany(p1, base + NN + n,   isf32));
    float qz = sane(ldany(p1, base + 2*NN + n, isf32));

    int idx = idxin[((long)qidx << 6) + lane] & 2047;
    const void* sp = (lane < 32) ? p1 : p2;
    float nx = sane(ldany(sp, base + idx,        isf32));
    float ny = sane(ldany(sp, base + NN + idx,   isf32));
    float nz = sane(ldany(sp, base + 2*NN + idx, isf32));

    float r0 = nx - qx, r1 = ny - qy, r2 = nz - qz;
    float ss = fmaf(r0, r0, fmaf(r1, r1, r2 * r2));
    float dist = sqrtf(fmaxf(ss, 1e-12f));

    const float* B1 = wsf + OFF_B1;
    const float* B2 = wsf + OFF_B2;
    const float* B3 = wsf + OFF_B3;

    s16x8 b1f[4];
    #pragma unroll
    for (int nt = 0; nt < 4; nt++) {
        int src = 16 * nt + c;
        float f0 = __shfl(r0, src, 64);
        float f1 = __shfl(r1, src, 64);
        float f2v = __shfl(r2, src, 64);
        float f3v = __shfl(dist, src, 64);
        uint16_t h0 = f2bf(f0), h1 = f2bf(f1), h2 = f2bf(f2v), h3 = f2bf(f3v);
        uint16_t l0 = f2bf(f0 - bf2f(h0)), l1 = f2bf(f1 - bf2f(h1));
        uint16_t l2 = f2bf(f2v - bf2f(h2)), l3 = f2bf(f3v - bf2f(h3));
        s16x8 v;
        bool qa = (q < 2);
        bool qb = (q == 0);
        v[0] = qa ? (short)h0 : (short)0;
        v[1] = qa ? (short)h1 : (short)0;
        v[2] = qa ? (short)h2 : (short)0;
        v[3] = qa ? (short)h3 : (short)0;
        v[4] = qb ? (short)l0 : (short)0;
        v[5] = qb ? (short)l1 : (short)0;
        v[6] = qb ? (short)l2 : (short)0;
        v[7] = qb ? (short)l3 : (short)0;
        b1f[nt] = v;
    }

    f32x4 d1[4][4];
    #pragma unroll
    for (int mt = 0; mt < 4; mt++) {
        s16x8 a1 = *(const s16x8*)(T1 + (16 * mt + c) * 32 + q * 8);
        f32x4 bias = *(const f32x4*)(B1 + 16 * mt + 4 * q);
        #pragma unroll
        for (int nt = 0; nt < 4; nt++) {
            d1[mt][nt] = __builtin_amdgcn_mfma_f32_16x16x32_bf16(a1, b1f[nt], bias, 0, 0, 0);
        }
    }

    auto mkfrag = [](const f32x4& dlo, const f32x4& dhi) -> s16x8 {
        return mk8(pk2(fmaxf(dlo[0], 0.f), fmaxf(dlo[1], 0.f)),
                   pk2(fmaxf(dlo[2], 0.f), fmaxf(dlo[3], 0.f)),
                   pk2(fmaxf(dhi[0], 0.f), fmaxf(dhi[1], 0.f)),
                   pk2(fmaxf(dhi[2], 0.f), fmaxf(dhi[3], 0.f)));
    };

    f32x4 d2[4][4];
    #pragma unroll
    for (int mt = 0; mt < 4; mt++) {
        f32x4 bias = *(const f32x4*)(B2 + 16 * mt + 4 * q);
        #pragma unroll
        for (int nt = 0; nt < 4; nt++) d2[mt][nt] = bias;
    }
    #pragma unroll
    for (int g = 0; g < 2; g++) {
        s16x8 fh[4];
        #pragma unroll
        for (int nt = 0; nt < 4; nt++) fh[nt] = mkfrag(d1[2*g][nt], d1[2*g+1][nt]);
        #pragma unroll
        for (int mt = 0; mt < 4; mt++) {
            s16x8 ah = *(const s16x8*)(T2H + (16 * mt + c) * 72 + 32 * g + 8 * q);
            s16x8 al = *(const s16x8*)(T2L + (16 * mt + c) * 72 + 32 * g + 8 * q);
            #pragma unroll
            for (int nt = 0; nt < 4; nt++) {
                f32x4 acc = d2[mt][nt];
                acc = __builtin_amdgcn_mfma_f32_16x16x32_bf16(ah, fh[nt], acc, 0, 0, 0);
                acc = __builtin_amdgcn_mfma_f32_16x16x32_bf16(al, fh[nt], acc, 0, 0, 0);
                d2[mt][nt] = acc;
            }
        }
    }

    s16x8 f3h[2][4];
    #pragma unroll
    for (int g = 0; g < 2; g++)
        #pragma unroll
        for (int nt = 0; nt < 4; nt++) f3h[g][nt] = mkfrag(d2[2*g][nt], d2[2*g+1][nt]);

    float mx[4] = {-1e30f, -1e30f, -1e30f, -1e30f};
    #pragma unroll
    for (int mt = 0; mt < 8; mt++) {
        f32x4 bias = *(const f32x4*)(B3 + 16 * mt + 4 * q);
        f32x4 acc[4];
        #pragma unroll
        for (int nt = 0; nt < 4; nt++) acc[nt] = bias;
        #pragma unroll
        for (int g = 0; g < 2; g++) {
            s16x8 ah = *(const s16x8*)(T3H + (16 * mt + c) * 72 + 32 * g + 8 * q);
            s16x8 al = *(const s16x8*)(T3L + (16 * mt + c) * 72 + 32 * g + 8 * q);
            #pragma unroll
            for (int nt = 0; nt < 4; nt++) {
                f32x4 a = acc[nt];
                a = __builtin_amdgcn_mfma_f32_16x16x32_bf16(ah, f3h[g][nt], a, 0, 0, 0);
                a = __builtin_amdgcn_mfma_f32_16x16x32_bf16(al, f3h[g][nt], a, 0, 0, 0);
                acc[nt] = a;
            }
        }
        #pragma unroll
        for (int nt = 0; nt < 4; nt++) {
            mx[nt] = fmaxf(mx[nt], fmaxf(fmaxf(acc[nt][0], acc[nt][1]), fmaxf(acc[nt][2], acc[nt][3])));
        }
    }

    #pragma unroll
    for (int nt = 0; nt < 4; nt++) {
        mx[nt] = fmaxf(mx[nt], __shfl_xor(mx[nt], 16, 64));
        mx[nt] = fmaxf(mx[nt], __shfl_xor(mx[nt], 32, 64));
        mx[nt] = fmaxf(mx[nt], 0.f);
    }
    float mall = fmaxf(fmaxf(mx[0], mx[1]), fmaxf(mx[2], mx[3]));
    #pragma unroll
    for (int m = 1; m < 16; m <<= 1) mall = fmaxf(mall, __shfl_xor(mall, m, 64));
    float e0 = __expf(mx[0] - mall), e1 = __expf(mx[1] - mall);
    float e2 = __expf(mx[2] - mall), e3 = __expf(mx[3] - mall);
    float s = e0 + e1 + e2 + e3;
    #pragma unroll
    for (int m = 1; m < 16; m <<= 1) s += __shfl_xor(s, m, 64);
    float eown = (q == 0) ? e0 : (q == 1) ? e1 : (q == 2) ? e2 : e3;
    float w = eown / s;

    float sx = w * nx, sy = w * ny, sz = w * nz;
    #pragma unroll
    for (int m = 1; m < 64; m <<= 1) {
        sx += __shfl_xor(sx, m, 64);
        sy += __shfl_xor(sy, m, 64);
        sz += __shfl_xor(sz, m, 64);
    }

    if (lane < 3) {
        float v = (lane == 0) ? sx : ((lane == 1) ? sy : sz);
        long oi = base + (long)lane * NN + n;
        if (isf32) {
            ((float*)outp)[oi] = v;
        } else {
            ((uint16_t*)outp)[oi] = f2bf(v);
        }
    }
}

extern "C" void kernel_launch(void* const* d_in, const int* in_sizes, int n_in,
                              void* d_out, int out_size, void* d_ws, size_t ws_size,
                              hipStream_t stream) {
    const void* p1 = d_in[0];
    const void* p2 = d_in[1];
    float* wsf = (float*)d_ws;
    int*   wsi = (int*)d_ws;
    uint16_t* idxbuf = (uint16_t*)((char*)d_ws + IDX_BYTE_OFF);

    k0_fold<<<64, 256, 0, stream>>>(p1,
        d_in[2],  d_in[3],  d_in[4],  d_in[5],  d_in[6],  d_in[7],
        d_in[8],  d_in[9],  d_in[10], d_in[11], d_in[12], d_in[13],
        d_in[14], d_in[15], d_in[16], d_in[17], d_in[18], d_in[19],
        wsf, wsi);

    k1_knn<<<(BB * NN) / 4, 256, 0, stream>>>(p1, p2, wsi, idxbuf);

    k2_mlp<<<(BB * NN) / 4, 256, 0, stream>>>(p1, p2, wsf, wsi, idxbuf, d_out);
}

// Round 15
// 289.614 us; speedup vs baseline: 1.0717x; 1.0717x over previous
//
#include <hip/hip_runtime.h>
#include <hip/hip_bf16.h>
#include <stdint.h>

#define BB 8
#define NN 2048

// ---- workspace layout ----
#define OFF_B1 272
#define OFF_B2 4432
#define OFF_B3 12688
#define IDX_BYTE_OFF 65536            // u16 idx[B][N][64] = 2 MiB
#define T_BASE   (65536 + 2*1024*1024)
#define T1_OFF   T_BASE               // [64][32] bf16, 4096 B
#define T2H_OFF  (T1_OFF + 4096)      // [64][72] bf16, K-permuted
#define T2L_OFF  (T2H_OFF + 9216)
#define T3H_OFF  (T2L_OFF + 9216)     // [128][72] bf16, K-permuted
#define T3L_OFF  (T3H_OFF + 18432)
// LDS half-offsets for k2's staged copy (full table block)
#define L_T1   0
#define L_T2H  2048
#define L_T2L  6656
#define L_T3H  11264
#define L_T3L  20480
#define L_HALVES 29696                // 59392 B = 3712 uint4

typedef __attribute__((ext_vector_type(4))) float f32x4;
typedef __attribute__((ext_vector_type(8))) short s16x8;

__device__ __forceinline__ float ldany(const void* p, long i, int isf32) {
    if (isf32) return ((const float*)p)[i];
    uint32_t u = ((uint32_t)((const uint16_t*)p)[i]) << 16;
    float f; __builtin_memcpy(&f, &u, 4); return f;
}
__device__ __forceinline__ uint16_t f2bf(float f) {
    uint32_t u; __builtin_memcpy(&u, &f, 4);
    return (uint16_t)((u + 0x7FFFu + ((u >> 16) & 1u)) >> 16);
}
__device__ __forceinline__ float bf2f(uint16_t h) {
    uint32_t u = ((uint32_t)h) << 16;
    float f; __builtin_memcpy(&f, &u, 4); return f;
}
__device__ __forceinline__ uint32_t pk2(float a, float b) {
    __hip_bfloat162 h = __float22bfloat162_rn(make_float2(a, b));
    uint32_t u; __builtin_memcpy(&u, &h, 4); return u;
}
__device__ __forceinline__ s16x8 mk8(uint32_t a, uint32_t b, uint32_t c, uint32_t d) {
    uint32_t t[4] = {a, b, c, d}; s16x8 r; __builtin_memcpy(&r, t, 16); return r;
}
__device__ __forceinline__ float sane(float v) {
    return (v == v && v > -1e30f && v < 1e30f) ? v : 0.f;
}
__device__ __forceinline__ int mbcnt64(unsigned long long m) {
    return __builtin_amdgcn_mbcnt_hi((uint32_t)(m >> 32),
           __builtin_amdgcn_mbcnt_lo((uint32_t)m, 0));
}
__device__ __forceinline__ int kperm_pos(int kk) {
    int g = kk >> 5, c5 = kk & 31;
    int sub = (c5 >> 4) & 1, q = (c5 >> 2) & 3, r = c5 & 3;
    return 32 * g + 8 * q + 4 * sub + r;
}

// ---------------- K0: parallel dtype detect + fold + padded K-permuted tables (R11-proven) ----------------
__global__ void k0_fold(const void* p1,
                        const void* W1, const void* b1, const void* g1, const void* be1, const void* m1, const void* v1,
                        const void* W2, const void* b2, const void* g2, const void* be2, const void* m2, const void* v2,
                        const void* W3, const void* b3, const void* g3, const void* be3, const void* m3, const void* v3,
                        float* wsf, int* wsi) {
    __shared__ int s_cnt;
    int t = threadIdx.x;
    if (t == 0) s_cnt = 0;
    __syncthreads();
    const uint16_t* u = (const uint16_t*)p1;
    int c = 0;
    for (int i = t; i < 4096; i += 256) {
        uint16_t x = u[i];
        uint32_t e = (x >> 7) & 0xFF;
        c += ((e >= 0x70 && e <= 0x84) || x == 0) ? 1 : 0;
    }
    atomicAdd(&s_cnt, c);
    __syncthreads();
    int isf32 = (s_cnt < 3686) ? 1 : 0;
    if (blockIdx.x == 0 && t == 0) wsi[0] = isf32;

    uint16_t* t1  = (uint16_t*)((char*)wsf + T1_OFF);
    uint16_t* t2h = (uint16_t*)((char*)wsf + T2H_OFF);
    uint16_t* t2l = (uint16_t*)((char*)wsf + T2L_OFF);
    uint16_t* t3h = (uint16_t*)((char*)wsf + T3H_OFF);
    uint16_t* t3l = (uint16_t*)((char*)wsf + T3L_OFF);

    int gid = blockIdx.x * 256 + t;
    if (gid < 4096) {
        int o = gid >> 6, kk = gid & 63;
        float s = ldany(g2, o, isf32) * rsqrtf(ldany(v2, o, isf32) + 1e-3f);
        float w = ldany(W2, gid, isf32) * s;
        uint16_t wh = f2bf(w);
        int pos = o * 72 + kperm_pos(kk);
        t2h[pos] = wh; t2l[pos] = f2bf(w - bf2f(wh));
    } else if (gid < 12288) {
        int e = gid - 4096;
        int o = e >> 6, kk = e & 63;
        float s = ldany(g3, o, isf32) * rsqrtf(ldany(v3, o, isf32) + 1e-3f);
        float w = ldany(W3, e, isf32) * s;
        uint16_t wh = f2bf(w);
        int pos = o * 72 + kperm_pos(kk);
        t3h[pos] = wh; t3l[pos] = f2bf(w - bf2f(wh));
    } else if (gid < 12544) {
        int e = gid - 12288;
        int co = e >> 2, cc = e & 3;
        float s = ldany(g1, co, isf32) * rsqrtf(ldany(v1, co, isf32) + 1e-3f);
        float w = ldany(W1, co*4 + cc, isf32) * s;
        uint16_t wh = f2bf(w), wl = f2bf(w - bf2f(wh));
        t1[co*32 + cc]     = wh;
        t1[co*32 + 4 + cc] = wh;
        t1[co*32 + 8 + cc] = wl;
    } else if (gid < 13824) {
        int e = gid - 12544;
        int co = e / 20, k = e - co * 20;
        t1[co*32 + 12 + k] = 0;
    } else if (gid < 13888) {
        int o = gid - 13824;
        float s = ldany(g1, o, isf32) * rsqrtf(ldany(v1, o, isf32) + 1e-3f);
        wsf[OFF_B1 + o] = (ldany(b1, o, isf32) - ldany(m1, o, isf32)) * s + ldany(be1, o, isf32);
    } else if (gid < 13952) {
        int o = gid - 13888;
        float s = ldany(g2, o, isf32) * rsqrtf(ldany(v2, o, isf32) + 1e-3f);
        wsf[OFF_B2 + o] = (ldany(b2, o, isf32) - ldany(m2, o, isf32)) * s + ldany(be2, o, isf32);
    } else if (gid < 14080) {
        int o = gid - 13952;
        float s = ldany(g3, o, isf32) * rsqrtf(ldany(v3, o, isf32) + 1e-3f);
        wsf[OFF_B3 + o] = (ldany(b3, o, isf32) - ldany(m3, o, isf32)) * s + ldany(be3, o, isf32);
    }
}

// ---------------- K1: dual-target exact top-32 KNN — R13 body + hard waves/EU clamp ----------------
// amdgpu_waves_per_eu(4,4): pin allocator target to 4 waves/EU (128 VGPR budget) so it stops
// spilling kbA/kbB to scratch to chase 8 waves/EU (R11/R13/R14 all landed at the 56-64 VGPR
// quantum = 8-wave target, re-reading 256 B/lane of scratch every bisection probe).
__attribute__((amdgpu_waves_per_eu(4, 4)))
__launch_bounds__(256)
__global__ void k1_knn(const void* p1, const void* p2, const int* wsi, uint16_t* idxout) {
    __shared__ unsigned long long smem[4 * 128];

    int isf32 = wsi[0];
    int lane = threadIdx.x & 63;
    int wave = threadIdx.x >> 6;
    int qidx = blockIdx.x * 4 + wave;
    int b = qidx >> 11, n = qidx & 2047;
    long base = (long)b * 3 * NN;

    float qx = ldany(p1, base + n,        isf32);
    float qy = ldany(p1, base + NN + n,   isf32);
    float qz = ldany(p1, base + 2*NN + n, isf32);
    float s1 = qx * qx + qy * qy + qz * qz;

    uint32_t kbA[32], kbB[32];
    if (!isf32) {
        // target A (p1): kbA[8i+2j+w] <-> idx 512i + 8*lane + 2j + w
        {
            const uint16_t* tpu = (const uint16_t*)p1 + base;
            const uint4* rx = (const uint4*)(tpu);
            const uint4* ry = (const uint4*)(tpu + NN);
            const uint4* rz = (const uint4*)(tpu + 2*NN);
            #pragma unroll
            for (int i = 0; i < 4; i++) {
                int v4 = i * 64 + lane;
                uint4 X = rx[v4], Y = ry[v4], Z = rz[v4];
                uint32_t xw[4] = {X.x, X.y, X.z, X.w};
                uint32_t yw[4] = {Y.x, Y.y, Y.z, Y.w};
                uint32_t zw[4] = {Z.x, Z.y, Z.z, Z.w};
                #pragma unroll
                for (int j = 0; j < 4; j++) {
                    #pragma unroll
                    for (int w = 0; w < 2; w++) {
                        uint32_t ux = (w == 0) ? (xw[j] << 16) : (xw[j] & 0xFFFF0000u);
                        uint32_t uy = (w == 0) ? (yw[j] << 16) : (yw[j] & 0xFFFF0000u);
                        uint32_t uz = (w == 0) ? (zw[j] << 16) : (zw[j] & 0xFFFF0000u);
                        float nx, ny, nz;
                        __builtin_memcpy(&nx, &ux, 4); __builtin_memcpy(&ny, &uy, 4); __builtin_memcpy(&nz, &uz, 4);
                        float s2  = nx * nx + ny * ny + nz * nz;
                        float dot = qx * nx + qy * ny + qz * nz;
                        float d2  = fmaxf((s1 + s2) - 2.0f * dot, 0.0f);
                        uint32_t bits; __builtin_memcpy(&bits, &d2, 4);
                        kbA[i*8 + j*2 + w] = bits;
                    }
                }
            }
        }
        // target B (p2)
        {
            const uint16_t* tpu = (const uint16_t*)p2 + base;
            const uint4* rx = (const uint4*)(tpu);
            const uint4* ry = (const uint4*)(tpu + NN);
            const uint4* rz = (const uint4*)(tpu + 2*NN);
            #pragma unroll
            for (int i = 0; i < 4; i++) {
                int v4 = i * 64 + lane;
                uint4 X = rx[v4], Y = ry[v4], Z = rz[v4];
                uint32_t xw[4] = {X.x, X.y, X.z, X.w};
                uint32_t yw[4] = {Y.x, Y.y, Y.z, Y.w};
                uint32_t zw[4] = {Z.x, Z.y, Z.z, Z.w};
                #pragma unroll
                for (int j = 0; j < 4; j++) {
                    #pragma unroll
                    for (int w = 0; w < 2; w++) {
                        uint32_t ux = (w == 0) ? (xw[j] << 16) : (xw[j] & 0xFFFF0000u);
                        uint32_t uy = (w == 0) ? (yw[j] << 16) : (yw[j] & 0xFFFF0000u);
                        uint32_t uz = (w == 0) ? (zw[j] << 16) : (zw[j] & 0xFFFF0000u);
                        float nx, ny, nz;
                        __builtin_memcpy(&nx, &ux, 4); __builtin_memcpy(&ny, &uy, 4); __builtin_memcpy(&nz, &uz, 4);
                        float s2  = nx * nx + ny * ny + nz * nz;
                        float dot = qx * nx + qy * ny + qz * nz;
                        float d2  = fmaxf((s1 + s2) - 2.0f * dot, 0.0f);
                        uint32_t bits; __builtin_memcpy(&bits, &d2, 4);
                        kbB[i*8 + j*2 + w] = bits;
                    }
                }
            }
        }
    } else {
        #pragma unroll
        for (int i = 0; i < 32; i++) {
            int j = i * 64 + lane;
            float ax = ldany(p1, base + j,        isf32);
            float ay = ldany(p1, base + NN + j,   isf32);
            float az = ldany(p1, base + 2*NN + j, isf32);
            float d2a = fmaxf((s1 + ax*ax + ay*ay + az*az) - 2.0f*(qx*ax + qy*ay + qz*az), 0.0f);
            uint32_t ba; __builtin_memcpy(&ba, &d2a, 4);
            kbA[i] = ba;
            float bx = ldany(p2, base + j,        isf32);
            float by = ldany(p2, base + NN + j,   isf32);
            float bz = ldany(p2, base + 2*NN + j, isf32);
            float d2b = fmaxf((s1 + bx*bx + by*by + bz*bz) - 2.0f*(qx*bx + qy*by + qz*bz), 0.0f);
            uint32_t bb; __builtin_memcpy(&bb, &d2b, 4);
            kbB[i] = bb;
        }
    }

    // ---- dual windowed bisection (accept count in [32,64]); ballot counts ----
    uint32_t loA = 0u, hiA = 0x7F800001u, tauA = 0u;
    uint32_t loB = 0u, hiB = 0x7F800001u, tauB = 0u;
    bool dA = false, dB = false;
    while (!(dA && dB)) {
        uint32_t midA = loA + ((hiA - loA) >> 1);
        uint32_t midB = loB + ((hiB - loB) >> 1);
        int cA = 0, cB = 0;
        #pragma unroll
        for (int i = 0; i < 32; i++) {
            cA += __builtin_popcountll(__ballot(kbA[i] < midA));
            cB += __builtin_popcountll(__ballot(kbB[i] < midB));
        }
        if (!dA) {
            if (cA < 32)      loA = midA;
            else if (cA > 64) hiA = midA;
            else { tauA = midA; dA = true; }
            if (!dA && hiA - loA <= 1u) { tauA = hiA; dA = true; }
        }
        if (!dB) {
            if (cB < 32)      loB = midB;
            else if (cB > 64) hiB = midB;
            else { tauB = midB; dB = true; }
            if (!dB && hiB - loB <= 1u) { tauB = hiB; dB = true; }
        }
    }

    // ---- survivors -> LDS via ballot+mbcnt ranks, sentinel fill ----
    unsigned long long* slA = smem + wave * 128;
    unsigned long long* slB = slA + 64;
    slA[lane] = ~0ull;
    slB[lane] = ~0ull;
    __syncthreads();
    int baseA = 0, baseB = 0;
    #pragma unroll
    for (int i = 0; i < 32; i++) {
        unsigned idxv = isf32 ? (unsigned)(i * 64 + lane)
                              : (unsigned)((i >> 3) * 512 + 8 * lane + (i & 7));
        bool pA = kbA[i] < tauA;
        unsigned long long mA = __ballot(pA);
        int posA = baseA + mbcnt64(mA);
        if (pA && posA < 64) slA[posA] = (((unsigned long long)kbA[i]) << 32) | idxv;
        baseA += __builtin_popcountll(mA);
        bool pB = kbB[i] < tauB;
        unsigned long long mB = __ballot(pB);
        int posB = baseB + mbcnt64(mB);
        if (pB && posB < 64) slB[posB] = (((unsigned long long)kbB[i]) << 32) | idxv;
        baseB += __builtin_popcountll(mB);
    }
    __syncthreads();
    unsigned long long keyA = slA[lane];
    unsigned long long keyB = slB[lane];

    // ---- interleaved dual bitonic sort 64 (ascending (d2bits, idx)) ----
    #pragma unroll
    for (int sz = 2; sz <= 64; sz <<= 1) {
        #pragma unroll
        for (int st = sz >> 1; st > 0; st >>= 1) {
            bool up    = ((lane & sz) == 0);
            bool lower = ((lane & st) == 0);
            unsigned long long otA = __shfl_xor(keyA, st, 64);
            unsigned long long otB = __shfl_xor(keyB, st, 64);
            unsigned long long mnA = (keyA < otA) ? keyA : otA;
            unsigned long long mxA = (keyA < otA) ? otA : keyA;
            keyA = (lower == up) ? mnA : mxA;
            unsigned long long mnB = (keyB < otB) ? keyB : otB;
            unsigned long long mxB = (keyB < otB) ? otB : keyB;
            keyB = (lower == up) ? mnB : mxB;
        }
    }

    if (lane < 32) {
        long obase = ((long)qidx) << 6;
        idxout[obase + lane]      = (uint16_t)(keyA & 0x7FFu);
        idxout[obase + 32 + lane] = (uint16_t)(keyB & 0x7FFu);
    }
}

// ---------------- K2: MFMA MLP — full LDS-staged weights, shuffle-free transitions (verbatim R12) ----------------
__launch_bounds__(256)
__global__ void k2_mlp(const void* p1, const void* p2, const float* __restrict__ wsf, const int* wsi,
                       const uint16_t* __restrict__ idxin, void* outp) {
    __shared__ uint4 shw4[L_HALVES / 8];

    {
        const uint4* src = (const uint4*)((const char*)wsf + T1_OFF);
        for (int i = threadIdx.x; i < L_HALVES / 8; i += 256) shw4[i] = src[i];
    }
    __syncthreads();
    const uint16_t* shw = (const uint16_t*)shw4;
    const uint16_t* T1  = shw + L_T1;
    const uint16_t* T2H = shw + L_T2H;
    const uint16_t* T2L = shw + L_T2L;
    const uint16_t* T3H = shw + L_T3H;
    const uint16_t* T3L = shw + L_T3L;

    int isf32 = wsi[0];
    int lane = threadIdx.x & 63;
    int wave = threadIdx.x >> 6;
    int c = lane & 15;
    int q = lane >> 4;
    int qidx = blockIdx.x * 4 + wave;
    int b = qidx >> 11, n = qidx & 2047;
    long base = (long)b * 3 * NN;

    float qx = sane(ldany(p1, base + n,        isf32));
    float qy = sane(ldany(p1, base + NN + n,   isf32));
    float qz = sane(ldany(p1, base + 2*NN + n, isf32));

    int idx = idxin[((long)qidx << 6) + lane] & 2047;
    const void* sp = (lane < 32) ? p1 : p2;
    float nx = sane(ldany(sp, base + idx,        isf32));
    float ny = sane(ldany(sp, base + NN + idx,   isf32));
    float nz = sane(ldany(sp, base + 2*NN + idx, isf32));

    float r0 = nx - qx, r1 = ny - qy, r2 = nz - qz;
    float ss = fmaf(r0, r0, fmaf(r1, r1, r2 * r2));
    float dist = sqrtf(fmaxf(ss, 1e-12f));

    const float* B1 = wsf + OFF_B1;
    const float* B2 = wsf + OFF_B2;
    const float* B3 = wsf + OFF_B3;

    s16x8 b1f[4];
    #pragma unroll
    for (int nt = 0; nt < 4; nt++) {
        int src = 16 * nt + c;
        float f0 = __shfl(r0, src, 64);
        float f1 = __shfl(r1, src, 64);
        float f2v = __shfl(r2, src, 64);
        float f3v = __shfl(dist, src, 64);
        uint16_t h0 = f2bf(f0), h1 = f2bf(f1), h2 = f2bf(f2v), h3 = f2bf(f3v);
        uint16_t l0 = f2bf(f0 - bf2f(h0)), l1 = f2bf(f1 - bf2f(h1));
        uint16_t l2 = f2bf(f2v - bf2f(h2)), l3 = f2bf(f3v - bf2f(h3));
        s16x8 v;
        bool qa = (q < 2);
        bool qb = (q == 0);
        v[0] = qa ? (short)h0 : (short)0;
        v[1] = qa ? (short)h1 : (short)0;
        v[2] = qa ? (short)h2 : (short)0;
        v[3] = qa ? (short)h3 : (short)0;
        v[4] = qb ? (short)l0 : (short)0;
        v[5] = qb ? (short)l1 : (short)0;
        v[6] = qb ? (short)l2 : (short)0;
        v[7] = qb ? (short)l3 : (short)0;
        b1f[nt] = v;
    }

    f32x4 d1[4][4];
    #pragma unroll
    for (int mt = 0; mt < 4; mt++) {
        s16x8 a1 = *(const s16x8*)(T1 + (16 * mt + c) * 32 + q * 8);
        f32x4 bias = *(const f32x4*)(B1 + 16 * mt + 4 * q);
        #pragma unroll
        for (int nt = 0; nt < 4; nt++) {
            d1[mt][nt] = __builtin_amdgcn_mfma_f32_16x16x32_bf16(a1, b1f[nt], bias, 0, 0, 0);
        }
    }

    auto mkfrag = [](const f32x4& dlo, const f32x4& dhi) -> s16x8 {
        return mk8(pk2(fmaxf(dlo[0], 0.f), fmaxf(dlo[1], 0.f)),
                   pk2(fmaxf(dlo[2], 0.f), fmaxf(dlo[3], 0.f)),
                   pk2(fmaxf(dhi[0], 0.f), fmaxf(dhi[1], 0.f)),
                   pk2(fmaxf(dhi[2], 0.f), fmaxf(dhi[3], 0.f)));
    };

    f32x4 d2[4][4];
    #pragma unroll
    for (int mt = 0; mt < 4; mt++) {
        f32x4 bias = *(const f32x4*)(B2 + 16 * mt + 4 * q);
        #pragma unroll
        for (int nt = 0; nt < 4; nt++) d2[mt][nt] = bias;
    }
    #pragma unroll
    for (int g = 0; g < 2; g++) {
        s16x8 fh[4];
        #pragma unroll
        for (int nt = 0; nt < 4; nt++) fh[nt] = mkfrag(d1[2*g][nt], d1[2*g+1][nt]);
        #pragma unroll
        for (int mt = 0; mt < 4; mt++) {
            s16x8 ah = *(const s16x8*)(T2H + (16 * mt + c) * 72 + 32 * g + 8 * q);
            s16x8 al = *(const s16x8*)(T2L + (16 * mt + c) * 72 + 32 * g + 8 * q);
            #pragma unroll
            for (int nt = 0; nt < 4; nt++) {
                f32x4 acc = d2[mt][nt];
                acc = __builtin_amdgcn_mfma_f32_16x16x32_bf16(ah, fh[nt], acc, 0, 0, 0);
                acc = __builtin_amdgcn_mfma_f32_16x16x32_bf16(al, fh[nt], acc, 0, 0, 0);
                d2[mt][nt] = acc;
            }
        }
    }

    s16x8 f3h[2][4];
    #pragma unroll
    for (int g = 0; g < 2; g++)
        #pragma unroll
        for (int nt = 0; nt < 4; nt++) f3h[g][nt] = mkfrag(d2[2*g][nt], d2[2*g+1][nt]);

    float mx[4] = {-1e30f, -1e30f, -1e30f, -1e30f};
    #pragma unroll
    for (int mt = 0; mt < 8; mt++) {
        f32x4 bias = *(const f32x4*)(B3 + 16 * mt + 4 * q);
        f32x4 acc[4];
        #pragma unroll
        for (int nt = 0; nt < 4; nt++) acc[nt] = bias;
        #pragma unroll
        for (int g = 0; g < 2; g++) {
            s16x8 ah = *(const s16x8*)(T3H + (16 * mt + c) * 72 + 32 * g + 8 * q);
            s16x8 al = *(const s16x8*)(T3L + (16 * mt + c) * 72 + 32 * g + 8 * q);
            #pragma unroll
            for (int nt = 0; nt < 4; nt++) {
                f32x4 a = acc[nt];
                a = __builtin_amdgcn_mfma_f32_16x16x32_bf16(ah, f3h[g][nt], a, 0, 0, 0);
                a = __builtin_amdgcn_mfma_f32_16x16x32_bf16(al, f3h[g][nt], a, 0, 0, 0);
                acc[nt] = a;
            }
        }
        #pragma unroll
        for (int nt = 0; nt < 4; nt++) {
            mx[nt] = fmaxf(mx[nt], fmaxf(fmaxf(acc[nt][0], acc[nt][1]), fmaxf(acc[nt][2], acc[nt][3])));
        }
    }

    #pragma unroll
    for (int nt = 0; nt < 4; nt++) {
        mx[nt] = fmaxf(mx[nt], __shfl_xor(mx[nt], 16, 64));
        mx[nt] = fmaxf(mx[nt], __shfl_xor(mx[nt], 32, 64));
        mx[nt] = fmaxf(mx[nt], 0.f);
    }
    float mall = fmaxf(fmaxf(mx[0], mx[1]), fmaxf(mx[2], mx[3]));
    #pragma unroll
    for (int m = 1; m < 16; m <<= 1) mall = fmaxf(mall, __shfl_xor(mall, m, 64));
    float e0 = __expf(mx[0] - mall), e1 = __expf(mx[1] - mall);
    float e2 = __expf(mx[2] - mall), e3 = __expf(mx[3] - mall);
    float s = e0 + e1 + e2 + e3;
    #pragma unroll
    for (int m = 1; m < 16; m <<= 1) s += __shfl_xor(s, m, 64);
    float eown = (q == 0) ? e0 : (q == 1) ? e1 : (q == 2) ? e2 : e3;
    float w = eown / s;

    float sx = w * nx, sy = w * ny, sz = w * nz;
    #pragma unroll
    for (int m = 1; m < 64; m <<= 1) {
        sx += __shfl_xor(sx, m, 64);
        sy += __shfl_xor(sy, m, 64);
        sz += __shfl_xor(sz, m, 64);
    }

    if (lane < 3) {
        float v = (lane == 0) ? sx : ((lane == 1) ? sy : sz);
        long oi = base + (long)lane * NN + n;
        if (isf32) {
            ((float*)outp)[oi] = v;
        } else {
            ((uint16_t*)outp)[oi] = f2bf(v);
        }
    }
}

extern "C" void kernel_launch(void* const* d_in, const int* in_sizes, int n_in,
                              void* d_out, int out_size, void* d_ws, size_t ws_size,
                              hipStream_t stream) {
    const void* p1 = d_in[0];
    const void* p2 = d_in[1];
    float* wsf = (float*)d_ws;
    int*   wsi = (int*)d_ws;
    uint16_t* idxbuf = (uint16_t*)((char*)d_ws + IDX_BYTE_OFF);

    k0_fold<<<64, 256, 0, stream>>>(p1,
        d_in[2],  d_in[3],  d_in[4],  d_in[5],  d_in[6],  d_in[7],
        d_in[8],  d_in[9],  d_in[10], d_in[11], d_in[12], d_in[13],
        d_in[14], d_in[15], d_in[16], d_in[17], d_in[18], d_in[19],
        wsf, wsi);

    k1_knn<<<(BB * NN) / 4, 256, 0, stream>>>(p1, p2, wsi, idxbuf);

    k2_mlp<<<(BB * NN) / 4, 256, 0, stream>>>(p1, p2, wsf, wsi, idxbuf, d_out);
}

// Round 16
// 268.605 us; speedup vs baseline: 1.1556x; 1.0782x over previous
//
#include <hip/hip_runtime.h>
#include <hip/hip_bf16.h>
#include <stdint.h>

#define BB 8
#define NN 2048

// ---- workspace layout ----
#define OFF_B1 272
#define OFF_B2 4432
#define OFF_B3 12688
#define IDX_BYTE_OFF 65536            // u16 idx[B][N][64] = 2 MiB
#define T_BASE   (65536 + 2*1024*1024)
#define T1_OFF   T_BASE               // [64][32] bf16, 4096 B
#define T2H_OFF  (T1_OFF + 4096)      // [64][72] bf16, K-permuted
#define T2L_OFF  (T2H_OFF + 9216)
#define T3H_OFF  (T2L_OFF + 9216)     // [128][72] bf16, K-permuted
#define T3L_OFF  (T3H_OFF + 18432)
// LDS half-offsets for k2's staged copy (full table block)
#define L_T1   0
#define L_T2H  2048
#define L_T2L  6656
#define L_T3H  11264
#define L_T3L  20480
#define L_HALVES 29696                // 59392 B = 3712 uint4

typedef __attribute__((ext_vector_type(4))) float f32x4;
typedef __attribute__((ext_vector_type(8))) short s16x8;

__device__ __forceinline__ float ldany(const void* p, long i, int isf32) {
    if (isf32) return ((const float*)p)[i];
    uint32_t u = ((uint32_t)((const uint16_t*)p)[i]) << 16;
    float f; __builtin_memcpy(&f, &u, 4); return f;
}
__device__ __forceinline__ uint16_t f2bf(float f) {
    uint32_t u; __builtin_memcpy(&u, &f, 4);
    return (uint16_t)((u + 0x7FFFu + ((u >> 16) & 1u)) >> 16);
}
__device__ __forceinline__ float bf2f(uint16_t h) {
    uint32_t u = ((uint32_t)h) << 16;
    float f; __builtin_memcpy(&f, &u, 4); return f;
}
__device__ __forceinline__ uint32_t pk2(float a, float b) {
    __hip_bfloat162 h = __float22bfloat162_rn(make_float2(a, b));
    uint32_t u; __builtin_memcpy(&u, &h, 4); return u;
}
__device__ __forceinline__ s16x8 mk8(uint32_t a, uint32_t b, uint32_t c, uint32_t d) {
    uint32_t t[4] = {a, b, c, d}; s16x8 r; __builtin_memcpy(&r, t, 16); return r;
}
__device__ __forceinline__ float sane(float v) {
    return (v == v && v > -1e30f && v < 1e30f) ? v : 0.f;
}
__device__ __forceinline__ int mbcnt64(unsigned long long m) {
    return __builtin_amdgcn_mbcnt_hi((uint32_t)(m >> 32),
           __builtin_amdgcn_mbcnt_lo((uint32_t)m, 0));
}
__device__ __forceinline__ int kperm_pos(int kk) {
    int g = kk >> 5, c5 = kk & 31;
    int sub = (c5 >> 4) & 1, q = (c5 >> 2) & 3, r = c5 & 3;
    return 32 * g + 8 * q + 4 * sub + r;
}

// ---------------- K0: parallel dtype detect + fold + padded K-permuted tables (R11-proven) ----------------
__global__ void k0_fold(const void* p1,
                        const void* W1, const void* b1, const void* g1, const void* be1, const void* m1, const void* v1,
                        const void* W2, const void* b2, const void* g2, const void* be2, const void* m2, const void* v2,
                        const void* W3, const void* b3, const void* g3, const void* be3, const void* m3, const void* v3,
                        float* wsf, int* wsi) {
    __shared__ int s_cnt;
    int t = threadIdx.x;
    if (t == 0) s_cnt = 0;
    __syncthreads();
    const uint16_t* u = (const uint16_t*)p1;
    int c = 0;
    for (int i = t; i < 4096; i += 256) {
        uint16_t x = u[i];
        uint32_t e = (x >> 7) & 0xFF;
        c += ((e >= 0x70 && e <= 0x84) || x == 0) ? 1 : 0;
    }
    atomicAdd(&s_cnt, c);
    __syncthreads();
    int isf32 = (s_cnt < 3686) ? 1 : 0;
    if (blockIdx.x == 0 && t == 0) wsi[0] = isf32;

    uint16_t* t1  = (uint16_t*)((char*)wsf + T1_OFF);
    uint16_t* t2h = (uint16_t*)((char*)wsf + T2H_OFF);
    uint16_t* t2l = (uint16_t*)((char*)wsf + T2L_OFF);
    uint16_t* t3h = (uint16_t*)((char*)wsf + T3H_OFF);
    uint16_t* t3l = (uint16_t*)((char*)wsf + T3L_OFF);

    int gid = blockIdx.x * 256 + t;
    if (gid < 4096) {
        int o = gid >> 6, kk = gid & 63;
        float s = ldany(g2, o, isf32) * rsqrtf(ldany(v2, o, isf32) + 1e-3f);
        float w = ldany(W2, gid, isf32) * s;
        uint16_t wh = f2bf(w);
        int pos = o * 72 + kperm_pos(kk);
        t2h[pos] = wh; t2l[pos] = f2bf(w - bf2f(wh));
    } else if (gid < 12288) {
        int e = gid - 4096;
        int o = e >> 6, kk = e & 63;
        float s = ldany(g3, o, isf32) * rsqrtf(ldany(v3, o, isf32) + 1e-3f);
        float w = ldany(W3, e, isf32) * s;
        uint16_t wh = f2bf(w);
        int pos = o * 72 + kperm_pos(kk);
        t3h[pos] = wh; t3l[pos] = f2bf(w - bf2f(wh));
    } else if (gid < 12544) {
        int e = gid - 12288;
        int co = e >> 2, cc = e & 3;
        float s = ldany(g1, co, isf32) * rsqrtf(ldany(v1, co, isf32) + 1e-3f);
        float w = ldany(W1, co*4 + cc, isf32) * s;
        uint16_t wh = f2bf(w), wl = f2bf(w - bf2f(wh));
        t1[co*32 + cc]     = wh;
        t1[co*32 + 4 + cc] = wh;
        t1[co*32 + 8 + cc] = wl;
    } else if (gid < 13824) {
        int e = gid - 12544;
        int co = e / 20, k = e - co * 20;
        t1[co*32 + 12 + k] = 0;
    } else if (gid < 13888) {
        int o = gid - 13824;
        float s = ldany(g1, o, isf32) * rsqrtf(ldany(v1, o, isf32) + 1e-3f);
        wsf[OFF_B1 + o] = (ldany(b1, o, isf32) - ldany(m1, o, isf32)) * s + ldany(be1, o, isf32);
    } else if (gid < 13952) {
        int o = gid - 13888;
        float s = ldany(g2, o, isf32) * rsqrtf(ldany(v2, o, isf32) + 1e-3f);
        wsf[OFF_B2 + o] = (ldany(b2, o, isf32) - ldany(m2, o, isf32)) * s + ldany(be2, o, isf32);
    } else if (gid < 14080) {
        int o = gid - 13952;
        float s = ldany(g3, o, isf32) * rsqrtf(ldany(v3, o, isf32) + 1e-3f);
        wsf[OFF_B3 + o] = (ldany(b3, o, isf32) - ldany(m3, o, isf32)) * s + ldany(be3, o, isf32);
    }
}

// ---- one-target exact top-32: compute 32 cands, windowed bisect, scatter, sort, write ----
// live set ~ kb[32]+overhead ~= 50 VGPR -> fits the allocator's preferred 64-VGPR/8-wave budget.
__device__ __forceinline__ void knn_target(const void* p, long base, int isf32, int lane,
                                           float qx, float qy, float qz, float s1,
                                           unsigned long long* sl, uint16_t* dst) {
    uint32_t kb[32];
    if (!isf32) {
        const uint16_t* tpu = (const uint16_t*)p + base;
        const uint4* rx = (const uint4*)(tpu);
        const uint4* ry = (const uint4*)(tpu + NN);
        const uint4* rz = (const uint4*)(tpu + 2*NN);
        #pragma unroll
        for (int i = 0; i < 4; i++) {
            int v4 = i * 64 + lane;
            uint4 X = rx[v4], Y = ry[v4], Z = rz[v4];
            uint32_t xw[4] = {X.x, X.y, X.z, X.w};
            uint32_t yw[4] = {Y.x, Y.y, Y.z, Y.w};
            uint32_t zw[4] = {Z.x, Z.y, Z.z, Z.w};
            #pragma unroll
            for (int j = 0; j < 4; j++) {
                #pragma unroll
                for (int w = 0; w < 2; w++) {
                    uint32_t ux = (w == 0) ? (xw[j] << 16) : (xw[j] & 0xFFFF0000u);
                    uint32_t uy = (w == 0) ? (yw[j] << 16) : (yw[j] & 0xFFFF0000u);
                    uint32_t uz = (w == 0) ? (zw[j] << 16) : (zw[j] & 0xFFFF0000u);
                    float nx, ny, nz;
                    __builtin_memcpy(&nx, &ux, 4); __builtin_memcpy(&ny, &uy, 4); __builtin_memcpy(&nz, &uz, 4);
                    float s2  = nx * nx + ny * ny + nz * nz;
                    float dot = qx * nx + qy * ny + qz * nz;
                    float d2  = fmaxf((s1 + s2) - 2.0f * dot, 0.0f);
                    uint32_t bits; __builtin_memcpy(&bits, &d2, 4);
                    kb[i*8 + j*2 + w] = bits;
                }
            }
        }
    } else {
        const float* tpf = (const float*)p + base;
        #pragma unroll
        for (int i = 0; i < 32; i++) {
            int j = i * 64 + lane;
            float nx = tpf[j];
            float ny = tpf[NN + j];
            float nz = tpf[2*NN + j];
            float s2  = nx * nx + ny * ny + nz * nz;
            float dot = qx * nx + qy * ny + qz * nz;
            float d2  = fmaxf((s1 + s2) - 2.0f * dot, 0.0f);
            uint32_t bits; __builtin_memcpy(&bits, &d2, 4);
            kb[i] = bits;
        }
    }

    // windowed bisection: accept count in [32,64] (R13/R15-proven semantics)
    uint32_t lo = 0u, hi = 0x7F800001u, tau = 0u;
    while (true) {
        uint32_t mid = lo + ((hi - lo) >> 1);
        int c = 0;
        #pragma unroll
        for (int i = 0; i < 32; i++) c += __builtin_popcountll(__ballot(kb[i] < mid));
        if (c < 32)      lo = mid;
        else if (c > 64) hi = mid;
        else { tau = mid; break; }
        if (hi - lo <= 1u) { tau = hi; break; }
    }

    // scatter survivors to wave-private LDS via ballot+mbcnt ranks (no barrier needed: same wave)
    sl[lane] = ~0ull;
    int basePos = 0;
    #pragma unroll
    for (int i = 0; i < 32; i++) {
        unsigned idxv = isf32 ? (unsigned)(i * 64 + lane)
                              : (unsigned)((i >> 3) * 512 + 8 * lane + (i & 7));
        bool pz = kb[i] < tau;
        unsigned long long m = __ballot(pz);
        int pos = basePos + mbcnt64(m);
        if (pz && pos < 64) sl[pos] = (((unsigned long long)kb[i]) << 32) | idxv;
        basePos += __builtin_popcountll(m);
    }
    unsigned long long key = sl[lane];

    // bitonic sort 64 ascending (d2bits, idx)
    #pragma unroll
    for (int sz = 2; sz <= 64; sz <<= 1) {
        #pragma unroll
        for (int st = sz >> 1; st > 0; st >>= 1) {
            unsigned long long ot = __shfl_xor(key, st, 64);
            bool up    = ((lane & sz) == 0);
            bool lower = ((lane & st) == 0);
            unsigned long long mn = (key < ot) ? key : ot;
            unsigned long long mx = (key < ot) ? ot : key;
            key = (lower == up) ? mn : mx;
        }
    }

    if (lane < 32) dst[lane] = (uint16_t)(key & 0x7FFu);
}

// ---------------- K1: dual-target top-32 — two sequential phases, 32-reg working set ----------------
__launch_bounds__(256)
__global__ void k1_knn(const void* p1, const void* p2, const int* wsi, uint16_t* idxout) {
    __shared__ unsigned long long smem[4 * 64];

    int isf32 = wsi[0];
    int lane = threadIdx.x & 63;
    int wave = threadIdx.x >> 6;
    int qidx = blockIdx.x * 4 + wave;
    int b = qidx >> 11, n = qidx & 2047;
    long base = (long)b * 3 * NN;

    float qx = ldany(p1, base + n,        isf32);
    float qy = ldany(p1, base + NN + n,   isf32);
    float qz = ldany(p1, base + 2*NN + n, isf32);
    float s1 = qx * qx + qy * qy + qz * qz;

    unsigned long long* sl = smem + wave * 64;
    long obase = ((long)qidx) << 6;

    // phase A: target p1
    knn_target(p1, base, isf32, lane, qx, qy, qz, s1, sl, idxout + obase);

    // fence: keep phase-B loads from being hoisted into phase A (would double liveness -> spill)
    __builtin_amdgcn_sched_barrier(0);
    asm volatile("" ::: "memory");

    // phase B: target p2
    knn_target(p2, base, isf32, lane, qx, qy, qz, s1, sl, idxout + obase + 32);
}

// ---------------- K2: MFMA MLP — full LDS-staged weights, shuffle-free transitions (verbatim R12/R15) ----------------
__launch_bounds__(256)
__global__ void k2_mlp(const void* p1, const void* p2, const float* __restrict__ wsf, const int* wsi,
                       const uint16_t* __restrict__ idxin, void* outp) {
    __shared__ uint4 shw4[L_HALVES / 8];

    {
        const uint4* src = (const uint4*)((const char*)wsf + T1_OFF);
        for (int i = threadIdx.x; i < L_HALVES / 8; i += 256) shw4[i] = src[i];
    }
    __syncthreads();
    const uint16_t* shw = (const uint16_t*)shw4;
    const uint16_t* T1  = shw + L_T1;
    const uint16_t* T2H = shw + L_T2H;
    const uint16_t* T2L = shw + L_T2L;
    const uint16_t* T3H = shw + L_T3H;
    const uint16_t* T3L = shw + L_T3L;

    int isf32 = wsi[0];
    int lane = threadIdx.x & 63;
    int wave = threadIdx.x >> 6;
    int c = lane & 15;
    int q = lane >> 4;
    int qidx = blockIdx.x * 4 + wave;
    int b = qidx >> 11, n = qidx & 2047;
    long base = (long)b * 3 * NN;

    float qx = sane(ldany(p1, base + n,        isf32));
    float qy = sane(ldany(p1, base + NN + n,   isf32));
    float qz = sane(ldany(p1, base + 2*NN + n, isf32));

    int idx = idxin[((long)qidx << 6) + lane] & 2047;
    const void* sp = (lane < 32) ? p1 : p2;
    float nx = sane(ldany(sp, base + idx,        isf32));
    float ny = sane(ldany(sp, base + NN + idx,   isf32));
    float nz = sane(ldany(sp, base + 2*NN + idx, isf32));

    float r0 = nx - qx, r1 = ny - qy, r2 = nz - qz;
    float ss = fmaf(r0, r0, fmaf(r1, r1, r2 * r2));
    float dist = sqrtf(fmaxf(ss, 1e-12f));

    const float* B1 = wsf + OFF_B1;
    const float* B2 = wsf + OFF_B2;
    const float* B3 = wsf + OFF_B3;

    s16x8 b1f[4];
    #pragma unroll
    for (int nt = 0; nt < 4; nt++) {
        int src = 16 * nt + c;
        float f0 = __shfl(r0, src, 64);
        float f1 = __shfl(r1, src, 64);
        float f2v = __shfl(r2, src, 64);
        float f3v = __shfl(dist, src, 64);
        uint16_t h0 = f2bf(f0), h1 = f2bf(f1), h2 = f2bf(f2v), h3 = f2bf(f3v);
        uint16_t l0 = f2bf(f0 - bf2f(h0)), l1 = f2bf(f1 - bf2f(h1));
        uint16_t l2 = f2bf(f2v - bf2f(h2)), l3 = f2bf(f3v - bf2f(h3));
        s16x8 v;
        bool qa = (q < 2);
        bool qb = (q == 0);
        v[0] = qa ? (short)h0 : (short)0;
        v[1] = qa ? (short)h1 : (short)0;
        v[2] = qa ? (short)h2 : (short)0;
        v[3] = qa ? (short)h3 : (short)0;
        v[4] = qb ? (short)l0 : (short)0;
        v[5] = qb ? (short)l1 : (short)0;
        v[6] = qb ? (short)l2 : (short)0;
        v[7] = qb ? (short)l3 : (short)0;
        b1f[nt] = v;
    }

    f32x4 d1[4][4];
    #pragma unroll
    for (int mt = 0; mt < 4; mt++) {
        s16x8 a1 = *(const s16x8*)(T1 + (16 * mt + c) * 32 + q * 8);
        f32x4 bias = *(const f32x4*)(B1 + 16 * mt + 4 * q);
        #pragma unroll
        for (int nt = 0; nt < 4; nt++) {
            d1[mt][nt] = __builtin_amdgcn_mfma_f32_16x16x32_bf16(a1, b1f[nt], bias, 0, 0, 0);
        }
    }

    auto mkfrag = [](const f32x4& dlo, const f32x4& dhi) -> s16x8 {
        return mk8(pk2(fmaxf(dlo[0], 0.f), fmaxf(dlo[1], 0.f)),
                   pk2(fmaxf(dlo[2], 0.f), fmaxf(dlo[3], 0.f)),
                   pk2(fmaxf(dhi[0], 0.f), fmaxf(dhi[1], 0.f)),
                   pk2(fmaxf(dhi[2], 0.f), fmaxf(dhi[3], 0.f)));
    };

    f32x4 d2[4][4];
    #pragma unroll
    for (int mt = 0; mt < 4; mt++) {
        f32x4 bias = *(const f32x4*)(B2 + 16 * mt + 4 * q);
        #pragma unroll
        for (int nt = 0; nt < 4; nt++) d2[mt][nt] = bias;
    }
    #pragma unroll
    for (int g = 0; g < 2; g++) {
        s16x8 fh[4];
        #pragma unroll
        for (int nt = 0; nt < 4; nt++) fh[nt] = mkfrag(d1[2*g][nt], d1[2*g+1][nt]);
        #pragma unroll
        for (int mt = 0; mt < 4; mt++) {
            s16x8 ah = *(const s16x8*)(T2H + (16 * mt + c) * 72 + 32 * g + 8 * q);
            s16x8 al = *(const s16x8*)(T2L + (16 * mt + c) * 72 + 32 * g + 8 * q);
            #pragma unroll
            for (int nt = 0; nt < 4; nt++) {
                f32x4 acc = d2[mt][nt];
                acc = __builtin_amdgcn_mfma_f32_16x16x32_bf16(ah, fh[nt], acc, 0, 0, 0);
                acc = __builtin_amdgcn_mfma_f32_16x16x32_bf16(al, fh[nt], acc, 0, 0, 0);
                d2[mt][nt] = acc;
            }
        }
    }

    s16x8 f3h[2][4];
    #pragma unroll
    for (int g = 0; g < 2; g++)
        #pragma unroll
        for (int nt = 0; nt < 4; nt++) f3h[g][nt] = mkfrag(d2[2*g][nt], d2[2*g+1][nt]);

    float mx[4] = {-1e30f, -1e30f, -1e30f, -1e30f};
    #pragma unroll
    for (int mt = 0; mt < 8; mt++) {
        f32x4 bias = *(const f32x4*)(B3 + 16 * mt + 4 * q);
        f32x4 acc[4];
        #pragma unroll
        for (int nt = 0; nt < 4; nt++) acc[nt] = bias;
        #pragma unroll
        for (int g = 0; g < 2; g++) {
            s16x8 ah = *(const s16x8*)(T3H + (16 * mt + c) * 72 + 32 * g + 8 * q);
            s16x8 al = *(const s16x8*)(T3L + (16 * mt + c) * 72 + 32 * g + 8 * q);
            #pragma unroll
            for (int nt = 0; nt < 4; nt++) {
                f32x4 a = acc[nt];
                a = __builtin_amdgcn_mfma_f32_16x16x32_bf16(ah, f3h[g][nt], a, 0, 0, 0);
                a = __builtin_amdgcn_mfma_f32_16x16x32_bf16(al, f3h[g][nt], a, 0, 0, 0);
                acc[nt] = a;
            }
        }
        #pragma unroll
        for (int nt = 0; nt < 4; nt++) {
            mx[nt] = fmaxf(mx[nt], fmaxf(fmaxf(acc[nt][0], acc[nt][1]), fmaxf(acc[nt][2], acc[nt][3])));
        }
    }

    #pragma unroll
    for (int nt = 0; nt < 4; nt++) {
        mx[nt] = fmaxf(mx[nt], __shfl_xor(mx[nt], 16, 64));
        mx[nt] = fmaxf(mx[nt], __shfl_xor(mx[nt], 32, 64));
        mx[nt] = fmaxf(mx[nt], 0.f);
    }
    float mall = fmaxf(fmaxf(mx[0], mx[1]), fmaxf(mx[2], mx[3]));
    #pragma unroll
    for (int m = 1; m < 16; m <<= 1) mall = fmaxf(mall, __shfl_xor(mall, m, 64));
    float e0 = __expf(mx[0] - mall), e1 = __expf(mx[1] - mall);
    float e2 = __expf(mx[2] - mall), e3 = __expf(mx[3] - mall);
    float s = e0 + e1 + e2 + e3;
    #pragma unroll
    for (int m = 1; m < 16; m <<= 1) s += __shfl_xor(s, m, 64);
    float eown = (q == 0) ? e0 : (q == 1) ? e1 : (q == 2) ? e2 : e3;
    float w = eown / s;

    float sx = w * nx, sy = w * ny, sz = w * nz;
    #pragma unroll
    for (int m = 1; m < 64; m <<= 1) {
        sx += __shfl_xor(sx, m, 64);
        sy += __shfl_xor(sy, m, 64);
        sz += __shfl_xor(sz, m, 64);
    }

    if (lane < 3) {
        float v = (lane == 0) ? sx : ((lane == 1) ? sy : sz);
        long oi = base + (long)lane * NN + n;
        if (isf32) {
            ((float*)outp)[oi] = v;
        } else {
            ((uint16_t*)outp)[oi] = f2bf(v);
        }
    }
}

extern "C" void kernel_launch(void* const* d_in, const int* in_sizes, int n_in,
                              void* d_out, int out_size, void* d_ws, size_t ws_size,
                              hipStream_t stream) {
    const void* p1 = d_in[0];
    const void* p2 = d_in[1];
    float* wsf = (float*)d_ws;
    int*   wsi = (int*)d_ws;
    uint16_t* idxbuf = (uint16_t*)((char*)d_ws + IDX_BYTE_OFF);

    k0_fold<<<64, 256, 0, stream>>>(p1,
        d_in[2],  d_in[3],  d_in[4],  d_in[5],  d_in[6],  d_in[7],
        d_in[8],  d_in[9],  d_in[10], d_in[11], d_in[12], d_in[13],
        d_in[14], d_in[15], d_in[16], d_in[17], d_in[18], d_in[19],
        wsf, wsi);

    k1_knn<<<(BB * NN) / 4, 256, 0, stream>>>(p1, p2, wsi, idxbuf);

    k2_mlp<<<(BB * NN) / 4, 256, 0, stream>>>(p1, p2, wsf, wsi, idxbuf, d_out);
}

// Round 17
// 263.902 us; speedup vs baseline: 1.1761x; 1.0178x over previous
//
#include <hip/hip_runtime.h>
#include <hip/hip_bf16.h>
#include <stdint.h>

#define BB 8
#define NN 2048

// ---- workspace layout ----
#define OFF_B1 272
#define OFF_B2 4432
#define OFF_B3 12688
#define IDX_BYTE_OFF 65536            // u16 idx[B][N][64] = 2 MiB
#define T_BASE   (65536 + 2*1024*1024)
#define T1_OFF   T_BASE               // [64][32] bf16, 4096 B
#define T2H_OFF  (T1_OFF + 4096)      // [64][72] bf16, K-permuted
#define T2L_OFF  (T2H_OFF + 9216)
#define T3H_OFF  (T2L_OFF + 9216)     // [128][72] bf16, K-permuted
#define T3L_OFF  (T3H_OFF + 18432)
// LDS half-offsets for k2's staged copy (full table block)
#define L_T1   0
#define L_T2H  2048
#define L_T2L  6656
#define L_T3H  11264
#define L_T3L  20480
#define L_HALVES 29696                // 59392 B = 3712 uint4

typedef __attribute__((ext_vector_type(4))) float f32x4;
typedef __attribute__((ext_vector_type(8))) short s16x8;

__device__ __forceinline__ float ldany(const void* p, long i, int isf32) {
    if (isf32) return ((const float*)p)[i];
    uint32_t u = ((uint32_t)((const uint16_t*)p)[i]) << 16;
    float f; __builtin_memcpy(&f, &u, 4); return f;
}
__device__ __forceinline__ uint16_t f2bf(float f) {
    uint32_t u; __builtin_memcpy(&u, &f, 4);
    return (uint16_t)((u + 0x7FFFu + ((u >> 16) & 1u)) >> 16);
}
__device__ __forceinline__ float bf2f(uint16_t h) {
    uint32_t u = ((uint32_t)h) << 16;
    float f; __builtin_memcpy(&f, &u, 4); return f;
}
__device__ __forceinline__ uint32_t pk2(float a, float b) {
    __hip_bfloat162 h = __float22bfloat162_rn(make_float2(a, b));
    uint32_t u; __builtin_memcpy(&u, &h, 4); return u;
}
__device__ __forceinline__ s16x8 mk8(uint32_t a, uint32_t b, uint32_t c, uint32_t d) {
    uint32_t t[4] = {a, b, c, d}; s16x8 r; __builtin_memcpy(&r, t, 16); return r;
}
__device__ __forceinline__ float sane(float v) {
    return (v == v && v > -1e30f && v < 1e30f) ? v : 0.f;
}
__device__ __forceinline__ int mbcnt64(unsigned long long m) {
    return __builtin_amdgcn_mbcnt_hi((uint32_t)(m >> 32),
           __builtin_amdgcn_mbcnt_lo((uint32_t)m, 0));
}
__device__ __forceinline__ int kperm_pos(int kk) {
    int g = kk >> 5, c5 = kk & 31;
    int sub = (c5 >> 4) & 1, q = (c5 >> 2) & 3, r = c5 & 3;
    return 32 * g + 8 * q + 4 * sub + r;
}

// ---------------- K0: parallel dtype detect + fold + padded K-permuted tables (R11-proven) ----------------
__global__ void k0_fold(const void* p1,
                        const void* W1, const void* b1, const void* g1, const void* be1, const void* m1, const void* v1,
                        const void* W2, const void* b2, const void* g2, const void* be2, const void* m2, const void* v2,
                        const void* W3, const void* b3, const void* g3, const void* be3, const void* m3, const void* v3,
                        float* wsf, int* wsi) {
    __shared__ int s_cnt;
    int t = threadIdx.x;
    if (t == 0) s_cnt = 0;
    __syncthreads();
    const uint16_t* u = (const uint16_t*)p1;
    int c = 0;
    for (int i = t; i < 4096; i += 256) {
        uint16_t x = u[i];
        uint32_t e = (x >> 7) & 0xFF;
        c += ((e >= 0x70 && e <= 0x84) || x == 0) ? 1 : 0;
    }
    atomicAdd(&s_cnt, c);
    __syncthreads();
    int isf32 = (s_cnt < 3686) ? 1 : 0;
    if (blockIdx.x == 0 && t == 0) wsi[0] = isf32;

    uint16_t* t1  = (uint16_t*)((char*)wsf + T1_OFF);
    uint16_t* t2h = (uint16_t*)((char*)wsf + T2H_OFF);
    uint16_t* t2l = (uint16_t*)((char*)wsf + T2L_OFF);
    uint16_t* t3h = (uint16_t*)((char*)wsf + T3H_OFF);
    uint16_t* t3l = (uint16_t*)((char*)wsf + T3L_OFF);

    int gid = blockIdx.x * 256 + t;
    if (gid < 4096) {
        int o = gid >> 6, kk = gid & 63;
        float s = ldany(g2, o, isf32) * rsqrtf(ldany(v2, o, isf32) + 1e-3f);
        float w = ldany(W2, gid, isf32) * s;
        uint16_t wh = f2bf(w);
        int pos = o * 72 + kperm_pos(kk);
        t2h[pos] = wh; t2l[pos] = f2bf(w - bf2f(wh));
    } else if (gid < 12288) {
        int e = gid - 4096;
        int o = e >> 6, kk = e & 63;
        float s = ldany(g3, o, isf32) * rsqrtf(ldany(v3, o, isf32) + 1e-3f);
        float w = ldany(W3, e, isf32) * s;
        uint16_t wh = f2bf(w);
        int pos = o * 72 + kperm_pos(kk);
        t3h[pos] = wh; t3l[pos] = f2bf(w - bf2f(wh));
    } else if (gid < 12544) {
        int e = gid - 12288;
        int co = e >> 2, cc = e & 3;
        float s = ldany(g1, co, isf32) * rsqrtf(ldany(v1, co, isf32) + 1e-3f);
        float w = ldany(W1, co*4 + cc, isf32) * s;
        uint16_t wh = f2bf(w), wl = f2bf(w - bf2f(wh));
        t1[co*32 + cc]     = wh;
        t1[co*32 + 4 + cc] = wh;
        t1[co*32 + 8 + cc] = wl;
    } else if (gid < 13824) {
        int e = gid - 12544;
        int co = e / 20, k = e - co * 20;
        t1[co*32 + 12 + k] = 0;
    } else if (gid < 13888) {
        int o = gid - 13824;
        float s = ldany(g1, o, isf32) * rsqrtf(ldany(v1, o, isf32) + 1e-3f);
        wsf[OFF_B1 + o] = (ldany(b1, o, isf32) - ldany(m1, o, isf32)) * s + ldany(be1, o, isf32);
    } else if (gid < 13952) {
        int o = gid - 13888;
        float s = ldany(g2, o, isf32) * rsqrtf(ldany(v2, o, isf32) + 1e-3f);
        wsf[OFF_B2 + o] = (ldany(b2, o, isf32) - ldany(m2, o, isf32)) * s + ldany(be2, o, isf32);
    } else if (gid < 14080) {
        int o = gid - 13952;
        float s = ldany(g3, o, isf32) * rsqrtf(ldany(v3, o, isf32) + 1e-3f);
        wsf[OFF_B3 + o] = (ldany(b3, o, isf32) - ldany(m3, o, isf32)) * s + ldany(be3, o, isf32);
    }
}

// ---- one-target exact top-32 (R16-proven): 32 cands, windowed bisect, scatter, sort, write ----
__device__ __forceinline__ void knn_target(const void* p, long base, int isf32, int lane,
                                           float qx, float qy, float qz, float s1,
                                           unsigned long long* sl, uint16_t* dst) {
    uint32_t kb[32];
    if (!isf32) {
        const uint16_t* tpu = (const uint16_t*)p + base;
        const uint4* rx = (const uint4*)(tpu);
        const uint4* ry = (const uint4*)(tpu + NN);
        const uint4* rz = (const uint4*)(tpu + 2*NN);
        #pragma unroll
        for (int i = 0; i < 4; i++) {
            int v4 = i * 64 + lane;
            uint4 X = rx[v4], Y = ry[v4], Z = rz[v4];
            uint32_t xw[4] = {X.x, X.y, X.z, X.w};
            uint32_t yw[4] = {Y.x, Y.y, Y.z, Y.w};
            uint32_t zw[4] = {Z.x, Z.y, Z.z, Z.w};
            #pragma unroll
            for (int j = 0; j < 4; j++) {
                #pragma unroll
                for (int w = 0; w < 2; w++) {
                    uint32_t ux = (w == 0) ? (xw[j] << 16) : (xw[j] & 0xFFFF0000u);
                    uint32_t uy = (w == 0) ? (yw[j] << 16) : (yw[j] & 0xFFFF0000u);
                    uint32_t uz = (w == 0) ? (zw[j] << 16) : (zw[j] & 0xFFFF0000u);
                    float nx, ny, nz;
                    __builtin_memcpy(&nx, &ux, 4); __builtin_memcpy(&ny, &uy, 4); __builtin_memcpy(&nz, &uz, 4);
                    float s2  = nx * nx + ny * ny + nz * nz;
                    float dot = qx * nx + qy * ny + qz * nz;
                    float d2  = fmaxf((s1 + s2) - 2.0f * dot, 0.0f);
                    uint32_t bits; __builtin_memcpy(&bits, &d2, 4);
                    kb[i*8 + j*2 + w] = bits;
                }
            }
        }
    } else {
        const float* tpf = (const float*)p + base;
        #pragma unroll
        for (int i = 0; i < 32; i++) {
            int j = i * 64 + lane;
            float nx = tpf[j];
            float ny = tpf[NN + j];
            float nz = tpf[2*NN + j];
            float s2  = nx * nx + ny * ny + nz * nz;
            float dot = qx * nx + qy * ny + qz * nz;
            float d2  = fmaxf((s1 + s2) - 2.0f * dot, 0.0f);
            uint32_t bits; __builtin_memcpy(&bits, &d2, 4);
            kb[i] = bits;
        }
    }

    uint32_t lo = 0u, hi = 0x7F800001u, tau = 0u;
    while (true) {
        uint32_t mid = lo + ((hi - lo) >> 1);
        int c = 0;
        #pragma unroll
        for (int i = 0; i < 32; i++) c += __builtin_popcountll(__ballot(kb[i] < mid));
        if (c < 32)      lo = mid;
        else if (c > 64) hi = mid;
        else { tau = mid; break; }
        if (hi - lo <= 1u) { tau = hi; break; }
    }

    sl[lane] = ~0ull;
    int basePos = 0;
    #pragma unroll
    for (int i = 0; i < 32; i++) {
        unsigned idxv = isf32 ? (unsigned)(i * 64 + lane)
                              : (unsigned)((i >> 3) * 512 + 8 * lane + (i & 7));
        bool pz = kb[i] < tau;
        unsigned long long m = __ballot(pz);
        int pos = basePos + mbcnt64(m);
        if (pz && pos < 64) sl[pos] = (((unsigned long long)kb[i]) << 32) | idxv;
        basePos += __builtin_popcountll(m);
    }
    unsigned long long key = sl[lane];

    #pragma unroll
    for (int sz = 2; sz <= 64; sz <<= 1) {
        #pragma unroll
        for (int st = sz >> 1; st > 0; st >>= 1) {
            unsigned long long ot = __shfl_xor(key, st, 64);
            bool up    = ((lane & sz) == 0);
            bool lower = ((lane & st) == 0);
            unsigned long long mn = (key < ot) ? key : ot;
            unsigned long long mx = (key < ot) ? ot : key;
            key = (lower == up) ? mn : mx;
        }
    }

    if (lane < 32) dst[lane] = (uint16_t)(key & 0x7FFu);
}

// ---------------- K1: dual-target top-32 — two sequential phases (verbatim R16) ----------------
__launch_bounds__(256)
__global__ void k1_knn(const void* p1, const void* p2, const int* wsi, uint16_t* idxout) {
    __shared__ unsigned long long smem[4 * 64];

    int isf32 = wsi[0];
    int lane = threadIdx.x & 63;
    int wave = threadIdx.x >> 6;
    int qidx = blockIdx.x * 4 + wave;
    int b = qidx >> 11, n = qidx & 2047;
    long base = (long)b * 3 * NN;

    float qx = ldany(p1, base + n,        isf32);
    float qy = ldany(p1, base + NN + n,   isf32);
    float qz = ldany(p1, base + 2*NN + n, isf32);
    float s1 = qx * qx + qy * qy + qz * qz;

    unsigned long long* sl = smem + wave * 64;
    long obase = ((long)qidx) << 6;

    knn_target(p1, base, isf32, lane, qx, qy, qz, s1, sl, idxout + obase);

    __builtin_amdgcn_sched_barrier(0);
    asm volatile("" ::: "memory");

    knn_target(p2, base, isf32, lane, qx, qy, qz, s1, sl, idxout + obase + 32);
}

// ---------------- K2: MFMA MLP — 1024-thread blocks (16 waves share the staged tables) ----------------
// LDS 59392 B/block, 2 blocks/CU -> 32 waves/CU (was 8 at 256-thread blocks). Per-wave code unchanged.
__launch_bounds__(1024)
__global__ void k2_mlp(const void* p1, const void* p2, const float* __restrict__ wsf, const int* wsi,
                       const uint16_t* __restrict__ idxin, void* outp) {
    __shared__ uint4 shw4[L_HALVES / 8];

    {
        const uint4* src = (const uint4*)((const char*)wsf + T1_OFF);
        for (int i = threadIdx.x; i < L_HALVES / 8; i += 1024) shw4[i] = src[i];
    }
    __syncthreads();
    const uint16_t* shw = (const uint16_t*)shw4;
    const uint16_t* T1  = shw + L_T1;
    const uint16_t* T2H = shw + L_T2H;
    const uint16_t* T2L = shw + L_T2L;
    const uint16_t* T3H = shw + L_T3H;
    const uint16_t* T3L = shw + L_T3L;

    int isf32 = wsi[0];
    int lane = threadIdx.x & 63;
    int wave = threadIdx.x >> 6;        // 0..15
    int c = lane & 15;
    int q = lane >> 4;
    int qidx = blockIdx.x * 16 + wave;  // 1024 blocks x 16 waves = 16384 queries
    int b = qidx >> 11, n = qidx & 2047;
    long base = (long)b * 3 * NN;

    float qx = sane(ldany(p1, base + n,        isf32));
    float qy = sane(ldany(p1, base + NN + n,   isf32));
    float qz = sane(ldany(p1, base + 2*NN + n, isf32));

    int idx = idxin[((long)qidx << 6) + lane] & 2047;
    const void* sp = (lane < 32) ? p1 : p2;
    float nx = sane(ldany(sp, base + idx,        isf32));
    float ny = sane(ldany(sp, base + NN + idx,   isf32));
    float nz = sane(ldany(sp, base + 2*NN + idx, isf32));

    float r0 = nx - qx, r1 = ny - qy, r2 = nz - qz;
    float ss = fmaf(r0, r0, fmaf(r1, r1, r2 * r2));
    float dist = sqrtf(fmaxf(ss, 1e-12f));

    const float* B1 = wsf + OFF_B1;
    const float* B2 = wsf + OFF_B2;
    const float* B3 = wsf + OFF_B3;

    s16x8 b1f[4];
    #pragma unroll
    for (int nt = 0; nt < 4; nt++) {
        int src = 16 * nt + c;
        float f0 = __shfl(r0, src, 64);
        float f1 = __shfl(r1, src, 64);
        float f2v = __shfl(r2, src, 64);
        float f3v = __shfl(dist, src, 64);
        uint16_t h0 = f2bf(f0), h1 = f2bf(f1), h2 = f2bf(f2v), h3 = f2bf(f3v);
        uint16_t l0 = f2bf(f0 - bf2f(h0)), l1 = f2bf(f1 - bf2f(h1));
        uint16_t l2 = f2bf(f2v - bf2f(h2)), l3 = f2bf(f3v - bf2f(h3));
        s16x8 v;
        bool qa = (q < 2);
        bool qb = (q == 0);
        v[0] = qa ? (short)h0 : (short)0;
        v[1] = qa ? (short)h1 : (short)0;
        v[2] = qa ? (short)h2 : (short)0;
        v[3] = qa ? (short)h3 : (short)0;
        v[4] = qb ? (short)l0 : (short)0;
        v[5] = qb ? (short)l1 : (short)0;
        v[6] = qb ? (short)l2 : (short)0;
        v[7] = qb ? (short)l3 : (short)0;
        b1f[nt] = v;
    }

    f32x4 d1[4][4];
    #pragma unroll
    for (int mt = 0; mt < 4; mt++) {
        s16x8 a1 = *(const s16x8*)(T1 + (16 * mt + c) * 32 + q * 8);
        f32x4 bias = *(const f32x4*)(B1 + 16 * mt + 4 * q);
        #pragma unroll
        for (int nt = 0; nt < 4; nt++) {
            d1[mt][nt] = __builtin_amdgcn_mfma_f32_16x16x32_bf16(a1, b1f[nt], bias, 0, 0, 0);
        }
    }

    auto mkfrag = [](const f32x4& dlo, const f32x4& dhi) -> s16x8 {
        return mk8(pk2(fmaxf(dlo[0], 0.f), fmaxf(dlo[1], 0.f)),
                   pk2(fmaxf(dlo[2], 0.f), fmaxf(dlo[3], 0.f)),
                   pk2(fmaxf(dhi[0], 0.f), fmaxf(dhi[1], 0.f)),
                   pk2(fmaxf(dhi[2], 0.f), fmaxf(dhi[3], 0.f)));
    };

    f32x4 d2[4][4];
    #pragma unroll
    for (int mt = 0; mt < 4; mt++) {
        f32x4 bias = *(const f32x4*)(B2 + 16 * mt + 4 * q);
        #pragma unroll
        for (int nt = 0; nt < 4; nt++) d2[mt][nt] = bias;
    }
    #pragma unroll
    for (int g = 0; g < 2; g++) {
        s16x8 fh[4];
        #pragma unroll
        for (int nt = 0; nt < 4; nt++) fh[nt] = mkfrag(d1[2*g][nt], d1[2*g+1][nt]);
        #pragma unroll
        for (int mt = 0; mt < 4; mt++) {
            s16x8 ah = *(const s16x8*)(T2H + (16 * mt + c) * 72 + 32 * g + 8 * q);
            s16x8 al = *(const s16x8*)(T2L + (16 * mt + c) * 72 + 32 * g + 8 * q);
            #pragma unroll
            for (int nt = 0; nt < 4; nt++) {
                f32x4 acc = d2[mt][nt];
                acc = __builtin_amdgcn_mfma_f32_16x16x32_bf16(ah, fh[nt], acc, 0, 0, 0);
                acc = __builtin_amdgcn_mfma_f32_16x16x32_bf16(al, fh[nt], acc, 0, 0, 0);
                d2[mt][nt] = acc;
            }
        }
    }

    s16x8 f3h[2][4];
    #pragma unroll
    for (int g = 0; g < 2; g++)
        #pragma unroll
        for (int nt = 0; nt < 4; nt++) f3h[g][nt] = mkfrag(d2[2*g][nt], d2[2*g+1][nt]);

    float mx[4] = {-1e30f, -1e30f, -1e30f, -1e30f};
    #pragma unroll
    for (int mt = 0; mt < 8; mt++) {
        f32x4 bias = *(const f32x4*)(B3 + 16 * mt + 4 * q);
        f32x4 acc[4];
        #pragma unroll
        for (int nt = 0; nt < 4; nt++) acc[nt] = bias;
        #pragma unroll
        for (int g = 0; g < 2; g++) {
            s16x8 ah = *(const s16x8*)(T3H + (16 * mt + c) * 72 + 32 * g + 8 * q);
            s16x8 al = *(const s16x8*)(T3L + (16 * mt + c) * 72 + 32 * g + 8 * q);
            #pragma unroll
            for (int nt = 0; nt < 4; nt++) {
                f32x4 a = acc[nt];
                a = __builtin_amdgcn_mfma_f32_16x16x32_bf16(ah, f3h[g][nt], a, 0, 0, 0);
                a = __builtin_amdgcn_mfma_f32_16x16x32_bf16(al, f3h[g][nt], a, 0, 0, 0);
                acc[nt] = a;
            }
        }
        #pragma unroll
        for (int nt = 0; nt < 4; nt++) {
            mx[nt] = fmaxf(mx[nt], fmaxf(fmaxf(acc[nt][0], acc[nt][1]), fmaxf(acc[nt][2], acc[nt][3])));
        }
    }

    #pragma unroll
    for (int nt = 0; nt < 4; nt++) {
        mx[nt] = fmaxf(mx[nt], __shfl_xor(mx[nt], 16, 64));
        mx[nt] = fmaxf(mx[nt], __shfl_xor(mx[nt], 32, 64));
        mx[nt] = fmaxf(mx[nt], 0.f);
    }
    float mall = fmaxf(fmaxf(mx[0], mx[1]), fmaxf(mx[2], mx[3]));
    #pragma unroll
    for (int m = 1; m < 16; m <<= 1) mall = fmaxf(mall, __shfl_xor(mall, m, 64));
    float e0 = __expf(mx[0] - mall), e1 = __expf(mx[1] - mall);
    float e2 = __expf(mx[2] - mall), e3 = __expf(mx[3] - mall);
    float s = e0 + e1 + e2 + e3;
    #pragma unroll
    for (int m = 1; m < 16; m <<= 1) s += __shfl_xor(s, m, 64);
    float eown = (q == 0) ? e0 : (q == 1) ? e1 : (q == 2) ? e2 : e3;
    float w = eown / s;

    float sx = w * nx, sy = w * ny, sz = w * nz;
    #pragma unroll
    for (int m = 1; m < 64; m <<= 1) {
        sx += __shfl_xor(sx, m, 64);
        sy += __shfl_xor(sy, m, 64);
        sz += __shfl_xor(sz, m, 64);
    }

    if (lane < 3) {
        float v = (lane == 0) ? sx : ((lane == 1) ? sy : sz);
        long oi = base + (long)lane * NN + n;
        if (isf32) {
            ((float*)outp)[oi] = v;
        } else {
            ((uint16_t*)outp)[oi] = f2bf(v);
        }
    }
}

extern "C" void kernel_launch(void* const* d_in, const int* in_sizes, int n_in,
                              void* d_out, int out_size, void* d_ws, size_t ws_size,
                              hipStream_t stream) {
    const void* p1 = d_in[0];
    const void* p2 = d_in[1];
    float* wsf = (float*)d_ws;
    int*   wsi = (int*)d_ws;
    uint16_t* idxbuf = (uint16_t*)((char*)d_ws + IDX_BYTE_OFF);

    k0_fold<<<64, 256, 0, stream>>>(p1,
        d_in[2],  d_in[3],  d_in[4],  d_in[5],  d_in[6],  d_in[7],
        d_in[8],  d_in[9],  d_in[10], d_in[11], d_in[12], d_in[13],
        d_in[14], d_in[15], d_in[16], d_in[17], d_in[18], d_in[19],
        wsf, wsi);

    k1_knn<<<(BB * NN) / 4, 256, 0, stream>>>(p1, p2, wsi, idxbuf);

    // 16 waves/block share one staged table copy: 1024 blocks
    k2_mlp<<<(BB * NN) / 16, 1024, 0, stream>>>(p1, p2, wsf, wsi, idxbuf, d_out);
}